// Round 10
// baseline (430.961 us; speedup 1.0000x reference)
//
#include <hip/hip_runtime.h>
#include <hip/hip_bf16.h>
#include <math.h>

typedef __hip_bfloat16 bf16;

#define DIMD 128
#define BB 8
#define LL 128
#define TT 512

// esym tile params
#define BMT 64
#define BKT 32
#define TGT_TILES 36   // 8*9/2 upper-tri tiles (N=512 / 64)
#define LIG_TILES 3    // 2*3/2 upper-tri tiles (N=128 / 64)

// cvt'd f32 weight region element offsets
#define CV_EMBW   0L
#define CV_GATW   (CV_EMBW + 54 * 128)
#define CV_GATA   (CV_GATW + 3 * 128 * 128)
#define CV_WB     (CV_GATA + 3 * 128 * 128)
#define CV_GGW    (CV_WB + 3 * 128)
#define CV_GGB    (CV_GGW + 3 * 2 * 128)
#define CV_DCW1   (CV_GGB + 4)
#define CV_VW1    (CV_DCW1 + 2 * 128 * 128)
#define CV_TOTAL  (CV_VW1 + 2 * 128 * 128)

// Runtime-dtype load of external inputs: bf==1 -> bf16, else f32.
__device__ __forceinline__ float LD(const void* p, long i, int bf) {
    if (bf) return __bfloat162float(((const bf16*)p)[i]);
    return ((const float*)p)[i];
}

// One-time: detect dtype (self-detect per block), zero accum, publish flagp,
// convert hot weights to f32 (branch-free GEMMs afterwards).
__global__ void init_cvt(const unsigned int* __restrict__ embw_raw,
                         const void* __restrict__ embW, const void* __restrict__ gatW,
                         const void* __restrict__ gatA, const void* __restrict__ gatWb,
                         const void* __restrict__ ggW, const void* __restrict__ ggb,
                         const void* __restrict__ dcW1, const void* __restrict__ vW1,
                         float* __restrict__ out, float* __restrict__ accum,
                         int* __restrict__ flagp) {
    __shared__ int cnts;
    int t = threadIdx.x;
    if (t == 0) cnts = 0;
    __syncthreads();
    unsigned int bword = (embw_raw[t] >> 8) & 0xffu;
    unsigned int e = bword & 0x7fu;
    if (e >= 0x38u && e <= 0x3fu) atomicAdd(&cnts, 1);
    __syncthreads();
    int bf = cnts > 128;
    if (blockIdx.x == 0) {
        if (t < 32) accum[t] = 0.0f;
        if (t == 0) *flagp = bf;
    }
    long i = (long)blockIdx.x * 256 + t;
    if (i >= CV_TOTAL) return;
    float v;
    if (i < CV_GATW)      v = LD(embW, i, bf);
    else if (i < CV_GATA) v = LD(gatW, i - CV_GATW, bf);
    else if (i < CV_WB)   v = LD(gatA, i - CV_GATA, bf);
    else if (i < CV_GGW)  v = LD(gatWb, i - CV_WB, bf);
    else if (i < CV_GGB)  v = LD(ggW, i - CV_GGW, bf);
    else if (i < CV_DCW1) { long j = i - CV_GGB; v = (j < 3) ? LD(ggb, j, bf) : 0.0f; }
    else if (i < CV_VW1)  v = LD(dcW1, i - CV_DCW1, bf);
    else                  v = LD(vW1, i - CV_VW1, bf);
    out[i] = v;
}

// Both-sides embedding: rows [0, BB*LL) from Xl, rest from Xt. K=54. f32 W.
__global__ void embed_both(const void* __restrict__ Xl, const void* __restrict__ Xt,
                           const float* __restrict__ Wf, float* __restrict__ out,
                           int K, const int* __restrict__ flagp) {
    __shared__ float xrow[DIMD];
    int bf = *flagp;
    int row = blockIdx.x;
    int d = threadIdx.x;
    const void* X; long r;
    if (row < BB * LL) { X = Xl; r = row; }
    else               { X = Xt; r = row - BB * LL; }
    if (d < K) xrow[d] = LD(X, r * K + d, bf);
    __syncthreads();
    float acc = 0.0f;
    for (int k = 0; k < K; ++k)
        acc = fmaf(xrow[k], Wf[(long)k * DIMD + d], acc);
    out[(long)row * DIMD + d] = acc;
}

// Fused [gate of previous layer] + h = x@W + Wb + hA = h@A.
// 4 rows/block, 256 threads, ILP-4 k-loops (two 64-halves per chain).
// P0/P1 = split-K hp partials of previous layer (unified row space).
// P0 aliases hA: each block reads its own rows before rewriting them.
__global__ void gemm_hha_gate(float* __restrict__ X, const float* __restrict__ P0,
                              const float* __restrict__ P1, const float* __restrict__ cvw,
                              int layer, int dogate,
                              float* __restrict__ hout, float* __restrict__ hAout) {
    __shared__ float xs[4][DIMD];
    __shared__ float hs[4][DIMD];
    __shared__ float gred[4][2];
    long row0 = (long)blockIdx.x * 4;
    int d = threadIdx.x & 127, rg = threadIdx.x >> 7;
    int w = threadIdx.x >> 6, lane = threadIdx.x & 63;
    long r0 = row0 + rg * 2, r1 = r0 + 1;
    float xv0 = X[r0 * DIMD + d];
    float xv1 = X[r1 * DIMD + d];
    if (dogate) {
        const float* gW = cvw + CV_GGW + (long)(layer - 1) * 2 * DIMD;
        float gb = cvw[CV_GGB + (layer - 1)];
        float hp0 = fmaxf(P0[r0 * DIMD + d] + P1[r0 * DIMD + d], 0.0f);
        float hp1 = fmaxf(P0[r1 * DIMD + d] + P1[r1 * DIMD + d], 0.0f);
        float s0 = xv0 * gW[d] + hp0 * gW[DIMD + d];
        float s1 = xv1 * gW[d] + hp1 * gW[DIMD + d];
#pragma unroll
        for (int s = 32; s > 0; s >>= 1) { s0 += __shfl_xor(s0, s); s1 += __shfl_xor(s1, s); }
        if (lane == 0) { gred[rg * 2 + 0][w & 1] = s0; gred[rg * 2 + 1][w & 1] = s1; }
        __syncthreads();
        float g0 = gred[rg * 2 + 0][0] + gred[rg * 2 + 0][1] + gb;
        float g1 = gred[rg * 2 + 1][0] + gred[rg * 2 + 1][1] + gb;
        float c0 = 1.0f / (1.0f + expf(-g0));
        float c1 = 1.0f / (1.0f + expf(-g1));
        xv0 = c0 * xv0 + (1.0f - c0) * hp0;
        xv1 = c1 * xv1 + (1.0f - c1) * hp1;
        X[r0 * DIMD + d] = xv0;   // gated x for the next consumer
        X[r1 * DIMD + d] = xv1;
    }
    xs[rg * 2 + 0][d] = xv0;
    xs[rg * 2 + 1][d] = xv1;
    __syncthreads();
    const float* W = cvw + CV_GATW + (long)layer * DIMD * DIMD;
    const float* A = cvw + CV_GATA + (long)layer * DIMD * DIMD;
    float b = cvw[CV_WB + layer * DIMD + d];
    const float* x0 = xs[rg * 2];
    const float* x1 = xs[rg * 2 + 1];
    float h0a = b, h0b = 0.0f, h1a = b, h1b = 0.0f;
#pragma unroll 4
    for (int k = 0; k < 64; ++k) {
        float w0 = W[(long)k * DIMD + d];
        float w1 = W[(long)(k + 64) * DIMD + d];
        h0a = fmaf(x0[k], w0, h0a);
        h0b = fmaf(x0[k + 64], w1, h0b);
        h1a = fmaf(x1[k], w0, h1a);
        h1b = fmaf(x1[k + 64], w1, h1b);
    }
    float h0 = h0a + h0b, h1 = h1a + h1b;
    long ob = r0 * DIMD + d;
    hout[ob] = h0; hout[ob + DIMD] = h1;
    hs[rg * 2][d] = h0; hs[rg * 2 + 1][d] = h1;
    __syncthreads();
    const float* g0p = hs[rg * 2];
    const float* g1p = hs[rg * 2 + 1];
    float a0a = 0.0f, a0b = 0.0f, a1a = 0.0f, a1b = 0.0f;
#pragma unroll 4
    for (int k = 0; k < 64; ++k) {
        float w0 = A[(long)k * DIMD + d];
        float w1 = A[(long)(k + 64) * DIMD + d];
        a0a = fmaf(g0p[k], w0, a0a);
        a0b = fmaf(g0p[k + 64], w1, a0b);
        a1a = fmaf(g1p[k], w0, a1a);
        a1b = fmaf(g1p[k + 64], w1, a1b);
    }
    hAout[ob] = a0a + a0b;
    hAout[ob + DIMD] = a1a + a1b;
}

// e[b,j,k] = hA_j . h_k + h_j . hA_k  (symmetric!). Batched GEMM, K=256.
// Upper-triangle tiles only; mirror-write the transpose into the lower tile.
__global__ void esym_both(const float* __restrict__ hA_t, const float* __restrict__ h_t,
                          float* __restrict__ e_t,
                          const float* __restrict__ hA_l, const float* __restrict__ h_l,
                          float* __restrict__ e_l) {
    __shared__ float At[BKT][BMT + 4];
    __shared__ float Bt[BKT][BMT + 4];
    int idx = blockIdx.x, b = blockIdx.y, t = threadIdx.x;
    const float *hA, *h; float* e; int N;
    if (idx < TGT_TILES) { hA = hA_t; h = h_t; e = e_t; N = TT; }
    else { idx -= TGT_TILES; hA = hA_l; h = h_l; e = e_l; N = LL; }
    int jt = (int)((sqrtf(8.0f * idx + 1.0f) - 1.0f) * 0.5f);
    while ((jt + 1) * (jt + 2) / 2 <= idx) ++jt;
    while (jt * (jt + 1) / 2 > idx) --jt;
    int kt = idx - jt * (jt + 1) / 2;   // kt <= jt
    const float* hAb = hA + (long)b * N * DIMD;
    const float* hb  = h  + (long)b * N * DIMD;
    int tm = t & 15, tn = t >> 4;
    int k4 = (t & 7) * 4;
    int row0 = t >> 3;
    float acc[4][4];
#pragma unroll
    for (int i = 0; i < 4; ++i)
#pragma unroll
        for (int jj = 0; jj < 4; ++jj) acc[i][jj] = 0.0f;

#pragma unroll
    for (int c = 0; c < 8; ++c) {
        const float* Ap = (c < 4) ? hAb : hb;
        const float* Bp = (c < 4) ? hb : hAb;
        int ko = (c & 3) * BKT;
        __syncthreads();
#pragma unroll
        for (int rr = 0; rr < 2; ++rr) {
            int row = row0 + rr * 32;
            float4 av = *(const float4*)&Ap[(long)(jt * BMT + row) * DIMD + ko + k4];
            float4 bv = *(const float4*)&Bp[(long)(kt * BMT + row) * DIMD + ko + k4];
            At[k4 + 0][row] = av.x; At[k4 + 1][row] = av.y;
            At[k4 + 2][row] = av.z; At[k4 + 3][row] = av.w;
            Bt[k4 + 0][row] = bv.x; Bt[k4 + 1][row] = bv.y;
            Bt[k4 + 2][row] = bv.z; Bt[k4 + 3][row] = bv.w;
        }
        __syncthreads();
#pragma unroll
        for (int k = 0; k < BKT; ++k) {
            float4 a4 = *(const float4*)&At[k][tm * 4];
            float4 b4 = *(const float4*)&Bt[k][tn * 4];
            float A[4] = {a4.x, a4.y, a4.z, a4.w};
            float Bv[4] = {b4.x, b4.y, b4.z, b4.w};
#pragma unroll
            for (int i = 0; i < 4; ++i)
#pragma unroll
                for (int jj = 0; jj < 4; ++jj)
                    acc[i][jj] = fmaf(A[i], Bv[jj], acc[i][jj]);
        }
    }
    long ebN = (long)b * N;
    long ebase = (ebN + jt * BMT + tm * 4) * N + kt * BMT + tn * 4;
#pragma unroll
    for (int i = 0; i < 4; ++i) {
        float4 v;
        v.x = acc[i][0]; v.y = acc[i][1]; v.z = acc[i][2]; v.w = acc[i][3];
        *(float4*)&e[ebase + (long)i * N] = v;
    }
    if (jt != kt) {   // mirror tile (transpose), also float4-coalesced
        long mbase = (ebN + kt * BMT + tn * 4) * N + jt * BMT + tm * 4;
#pragma unroll
        for (int jj = 0; jj < 4; ++jj) {
            float4 v;
            v.x = acc[0][jj]; v.y = acc[1][jj]; v.z = acc[2][jj]; v.w = acc[3][jj];
            *(float4*)&e[mbase + (long)jj * N] = v;
        }
    }
}

// Softmax one row (FULL row for m/sum), store only this block's k-half into
// attT (transposed [k_local][row], row stride 36 for aligned float4 reads).
template<int CNT>
__device__ __forceinline__ void sm_row_store(const float* __restrict__ erow,
                                             const void* __restrict__ adj,
                                             long adjbase, int bf, int kc,
                                             float* __restrict__ attTbase, int lr) {
    int lane = threadIdx.x & 63;
    float vals[CNT], av[CNT];
    float m = -3.4e38f;
#pragma unroll
    for (int i = 0; i < CNT; ++i) {
        int k = lane + i * 64;
        float a = LD(adj, adjbase + k, bf);
        float v = (a > 0.0f) ? erow[k] : -9e15f;
        av[i] = a; vals[i] = v;
        m = fmaxf(m, v);
    }
#pragma unroll
    for (int s = 32; s > 0; s >>= 1) m = fmaxf(m, __shfl_xor(m, s));
    float sum = 0.0f;
#pragma unroll
    for (int i = 0; i < CNT; ++i) { vals[i] = expf(vals[i] - m); sum += vals[i]; }
#pragma unroll
    for (int s = 32; s > 0; s >>= 1) sum += __shfl_xor(sum, s);
    float inv = 1.0f / sum;
#pragma unroll
    for (int i = 0; i < CNT; ++i) {
        if ((i / (CNT / 2)) == kc) {              // compile-time i, uniform kc
            int klocal = lane + (i % (CNT / 2)) * 64;
            attTbase[klocal * 36 + lr] = vals[i] * av[i] * inv;
        }
    }
}

// Fused att-softmax + hp partial GEMM. Grid (20, 2, BB).
// jt<16: target; else ligand. kc selects k-half (split-K=2).
// Phase 1: 4 waves x 8 rows compute full-row softmax of e (masked by adj);
//          this half's normalized att stored transposed in LDS attT.
// Phase 2: 32xD GEMM from attT x streamed h tiles -> P_kc (unified rows).
__global__ void hp_sm_both(const float* __restrict__ e_t, const float* __restrict__ h_t,
                           const void* __restrict__ adj_t,
                           const float* __restrict__ e_l, const float* __restrict__ h_l,
                           const void* __restrict__ adj_l,
                           float* __restrict__ P0, float* __restrict__ P1,
                           const int* __restrict__ flagp) {
    __shared__ float attT[256][36];   // [k_local][row], 36.9 KB
    __shared__ float Ht[32][DIMD];    // 16 KB
    int bf = *flagp;
    int jt = blockIdx.x, kc = blockIdx.y, b = blockIdx.z;
    int t = threadIdx.x;
    const float *e, *h; const void* adj; int N; long rowbase;
    if (jt < 16) { e = e_t; h = h_t; adj = adj_t; N = TT; rowbase = (long)BB * LL + (long)b * TT; }
    else { jt -= 16; e = e_l; h = h_l; adj = adj_l; N = LL; rowbase = (long)b * LL; }
    int half = N / 2;
    int koff = kc * half;
    const float* hb = h + (long)b * N * DIMD;
    // ---- phase 1: softmax (4 waves x 8 rows, no cross-wave deps) ----
    int w = t >> 6;
    if (N == TT) {
        for (int r = 0; r < 8; ++r) {
            int lr = w * 8 + r;
            long base = ((long)b * TT + jt * 32 + lr) * TT;
            sm_row_store<8>(e + base, adj, base, bf, kc, &attT[0][0], lr);
        }
    } else {
        for (int r = 0; r < 8; ++r) {
            int lr = w * 8 + r;
            long base = ((long)b * LL + jt * 32 + lr) * LL;
            sm_row_store<2>(e + base, adj, base, bf, kc, &attT[0][0], lr);
        }
    }
    // ---- phase 2: GEMM acc[i][j] = sum_k attT[k][tm*4+i] * h[koff+k][tn*4+j]
    int tm = t & 7, tn = t >> 3;
    int hk = t >> 5, hc4 = (t & 31) * 4;
    float acc[4][4] = {};
    for (int k0 = 0; k0 < half; k0 += 32) {
        __syncthreads();   // first iter: attT ready; later: Ht consumed
#pragma unroll
        for (int p = 0; p < 4; ++p)
            *(float4*)&Ht[hk + p * 8][hc4] =
                *(const float4*)&hb[(long)(koff + k0 + hk + p * 8) * DIMD + hc4];
        __syncthreads();
#pragma unroll
        for (int k = 0; k < 32; ++k) {
            float4 a4 = *(const float4*)&attT[k0 + k][tm * 4];
            float4 h4 = *(const float4*)&Ht[k][tn * 4];
            float A[4] = {a4.x, a4.y, a4.z, a4.w};
            float H[4] = {h4.x, h4.y, h4.z, h4.w};
#pragma unroll
            for (int i = 0; i < 4; ++i)
#pragma unroll
                for (int jj = 0; jj < 4; ++jj)
                    acc[i][jj] = fmaf(A[i], H[jj], acc[i][jj]);
        }
    }
    float* outp = (kc == 0) ? P0 : P1;
    long obase = (rowbase + jt * 32 + tm * 4) * DIMD + tn * 4;
#pragma unroll
    for (int i = 0; i < 4; ++i) {
        float4 v; v.x = acc[i][0]; v.y = acc[i][1]; v.z = acc[i][2]; v.w = acc[i][3];
        *(float4*)&outp[obase + (long)i * DIMD] = v;
    }
}

// Final-layer gate + both pair-MLP projections. blockIdx.y: 0=dc, 1=vdwA.
__global__ void proj_gate(const float* __restrict__ X, const float* __restrict__ P0,
                          const float* __restrict__ P1, const float* __restrict__ cvw,
                          const void* __restrict__ bdc, const void* __restrict__ bA,
                          long rowsplit, float* __restrict__ outdc, float* __restrict__ outA,
                          const int* __restrict__ flagp) {
    __shared__ float xs[4][DIMD];
    __shared__ float gred[4][2];
    int bf = *flagp;
    long row0 = (long)blockIdx.x * 4;
    int d = threadIdx.x & 127, rg = threadIdx.x >> 7;
    int w = threadIdx.x >> 6, lane = threadIdx.x & 63;
    long r0 = row0 + rg * 2, r1 = r0 + 1;
    float xv0 = X[r0 * DIMD + d];
    float xv1 = X[r1 * DIMD + d];
    {
        const float* gW = cvw + CV_GGW + 2L * 2 * DIMD;
        float gb = cvw[CV_GGB + 2];
        float hp0 = fmaxf(P0[r0 * DIMD + d] + P1[r0 * DIMD + d], 0.0f);
        float hp1 = fmaxf(P0[r1 * DIMD + d] + P1[r1 * DIMD + d], 0.0f);
        float s0 = xv0 * gW[d] + hp0 * gW[DIMD + d];
        float s1 = xv1 * gW[d] + hp1 * gW[DIMD + d];
#pragma unroll
        for (int s = 32; s > 0; s >>= 1) { s0 += __shfl_xor(s0, s); s1 += __shfl_xor(s1, s); }
        if (lane == 0) { gred[rg * 2 + 0][w & 1] = s0; gred[rg * 2 + 1][w & 1] = s1; }
        __syncthreads();
        float g0 = gred[rg * 2 + 0][0] + gred[rg * 2 + 0][1] + gb;
        float g1 = gred[rg * 2 + 1][0] + gred[rg * 2 + 1][1] + gb;
        float c0 = 1.0f / (1.0f + expf(-g0));
        float c1 = 1.0f / (1.0f + expf(-g1));
        xv0 = c0 * xv0 + (1.0f - c0) * hp0;
        xv1 = c1 * xv1 + (1.0f - c1) * hp1;
    }
    xs[rg * 2 + 0][d] = xv0;
    xs[rg * 2 + 1][d] = xv1;
    __syncthreads();
    const float* Wf = (blockIdx.y == 0) ? (cvw + CV_DCW1) : (cvw + CV_VW1);
    const void* bias = (blockIdx.y == 0) ? bdc : bA;
    float* out = (blockIdx.y == 0) ? outdc : outA;
    int sideb = row0 >= rowsplit;
    const float* W = Wf + (sideb ? (long)DIMD * DIMD : 0);
    float b0 = sideb ? 0.0f : LD(bias, d, bf);
    const float* x0 = xs[rg * 2];
    const float* x1 = xs[rg * 2 + 1];
    float a0a = b0, a0b = 0.0f, a1a = b0, a1b = 0.0f;
#pragma unroll 4
    for (int k = 0; k < 64; ++k) {
        float w0 = W[(long)k * DIMD + d];
        float w1 = W[(long)(k + 64) * DIMD + d];
        a0a = fmaf(x0[k], w0, a0a);
        a0b = fmaf(x0[k + 64], w1, a0b);
        a1a = fmaf(x1[k], w0, a1a);
        a1b = fmaf(x1[k + 64], w1, a1b);
    }
    long ob = r0 * DIMD + d;
    out[ob] = a0a + a0b;
    out[ob + DIMD] = a1a + a1b;
}

// Both transposes in one launch: z<BB -> (in0->out0, b=z), else (in1->out1).
__global__ void transpose_both(const float* __restrict__ in0, float* __restrict__ out0,
                               const float* __restrict__ in1, float* __restrict__ out1) {
    __shared__ float tile[32][33];
    int z = blockIdx.z;
    const float* in; float* outT; int b;
    if (z < BB) { in = in0; outT = out0; b = z; }
    else        { in = in1; outT = out1; b = z - BB; }
    int n0 = blockIdx.x * 32;
    int d0 = blockIdx.y * 32;
    int t = threadIdx.x;
    int tx = t & 31, ty = t >> 5;
    for (int r = ty; r < 32; r += 8)
        tile[r][tx] = in[((long)b * TT + n0 + r) * DIMD + d0 + tx];
    __syncthreads();
    for (int r = ty; r < 32; r += 8)
        outT[((long)b * DIMD + d0 + r) * TT + n0 + tx] = tile[tx][r];
}

// Pair energies. Block = (b, 2 ligand rows); lane handles tt = 2t, 2t+1.
// All end-phase scalars (tpos/trad/tval/ii) PREFETCHED before the dot loop so
// their HBM latency hides under the 128-iter L2-bound MLP dot phase.
__global__ void pair_energy(const float* __restrict__ ligdc, const float* __restrict__ tgtdcT,
                            const float* __restrict__ ligA, const float* __restrict__ tgtAT,
                            const void* __restrict__ dcW2, const void* __restrict__ dcb2,
                            const void* __restrict__ AW2, const void* __restrict__ Ab2,
                            const void* __restrict__ lpos, const void* __restrict__ tpos,
                            const void* __restrict__ lrad, const void* __restrict__ trad,
                            const void* __restrict__ lval, const void* __restrict__ tval,
                            const void* __restrict__ ii, float* __restrict__ accum,
                            const int* __restrict__ flagp) {
    int bf = *flagp;
    int l0 = blockIdx.x * 2, b = blockIdx.y, t = threadIdx.x;
    __shared__ __align__(16) float sdc0[DIMD], sdc1[DIMD], sA0[DIMD], sA1[DIMD];
    __shared__ __align__(16) float w2dc[DIMD], w2A[DIMD];
    __shared__ float redw[4][4];
    if (t < DIMD) {
        sdc0[t] = ligdc[((long)b * LL + l0) * DIMD + t];
        sA0[t]  = ligA [((long)b * LL + l0) * DIMD + t];
        w2dc[t] = LD(dcW2, t, bf);
        w2A[t]  = LD(AW2, t, bf);
    } else {
        int u = t - DIMD;
        sdc1[u] = ligdc[((long)b * LL + l0 + 1) * DIMD + u];
        sA1[u]  = ligA [((long)b * LL + l0 + 1) * DIMD + u];
    }
    int tt0 = t * 2;
    // ---- prefetch (issued before the dot loop; consumed after it) ----
    float tx0 = LD(tpos, ((long)b * TT + tt0) * 3 + 0, bf);
    float ty0 = LD(tpos, ((long)b * TT + tt0) * 3 + 1, bf);
    float tz0 = LD(tpos, ((long)b * TT + tt0) * 3 + 2, bf);
    float tx1 = LD(tpos, ((long)b * TT + tt0 + 1) * 3 + 0, bf);
    float ty1 = LD(tpos, ((long)b * TT + tt0 + 1) * 3 + 1, bf);
    float tz1 = LD(tpos, ((long)b * TT + tt0 + 1) * 3 + 2, bf);
    float tr0 = LD(trad, (long)b * TT + tt0, bf);
    float tr1 = LD(trad, (long)b * TT + tt0 + 1, bf);
    float tv0 = LD(tval, (long)b * TT + tt0, bf);
    float tv1 = LD(tval, (long)b * TT + tt0 + 1, bf);
    long iiA0 = ((long)(b * 3 + 0) * LL + l0) * TT;
    long iiB0 = ((long)(b * 3 + 1) * LL + l0) * TT;
    long iiC0 = ((long)(b * 3 + 2) * LL + l0) * TT;
    long iiA1 = iiA0 + TT, iiB1 = iiB0 + TT, iiC1 = iiC0 + TT;
    float iA00 = LD(ii, iiA0 + tt0, bf), iA01 = LD(ii, iiA0 + tt0 + 1, bf);
    float iA10 = LD(ii, iiA1 + tt0, bf), iA11 = LD(ii, iiA1 + tt0 + 1, bf);
    float iB00 = LD(ii, iiB0 + tt0, bf), iB01 = LD(ii, iiB0 + tt0 + 1, bf);
    float iB10 = LD(ii, iiB1 + tt0, bf), iB11 = LD(ii, iiB1 + tt0 + 1, bf);
    float iC00 = LD(ii, iiC0 + tt0, bf), iC01 = LD(ii, iiC0 + tt0 + 1, bf);
    float iC10 = LD(ii, iiC1 + tt0, bf), iC11 = LD(ii, iiC1 + tt0 + 1, bf);
    float lx0 = LD(lpos, ((long)b * LL + l0) * 3 + 0, bf);
    float ly0 = LD(lpos, ((long)b * LL + l0) * 3 + 1, bf);
    float lz0 = LD(lpos, ((long)b * LL + l0) * 3 + 2, bf);
    float lx1 = LD(lpos, ((long)b * LL + l0 + 1) * 3 + 0, bf);
    float ly1 = LD(lpos, ((long)b * LL + l0 + 1) * 3 + 1, bf);
    float lz1 = LD(lpos, ((long)b * LL + l0 + 1) * 3 + 2, bf);
    float lr0 = LD(lrad, (long)b * LL + l0, bf);
    float lr1 = LD(lrad, (long)b * LL + l0 + 1, bf);
    float lv0 = LD(lval, (long)b * LL + l0, bf);
    float lv1 = LD(lval, (long)b * LL + l0 + 1, bf);
    float cdcb2 = LD(dcb2, 0, bf), cab2 = LD(Ab2, 0, bf);
    __syncthreads();
    // ---- MLP dot loop (L2-bound; hides the prefetch latency) ----
    const float* tdT = tgtdcT + (long)b * DIMD * TT;
    const float* taT = tgtAT  + (long)b * DIMD * TT;
    float adc00 = 0.0f, adc01 = 0.0f, adc10 = 0.0f, adc11 = 0.0f;
    float aA00 = 0.0f, aA01 = 0.0f, aA10 = 0.0f, aA11 = 0.0f;
    for (int i4 = 0; i4 < DIMD; i4 += 4) {
        float4 wd = *(const float4*)&w2dc[i4];
        float4 wa = *(const float4*)&w2A[i4];
        float4 v0d = *(const float4*)&sdc0[i4];
        float4 v1d = *(const float4*)&sdc1[i4];
        float4 v0a = *(const float4*)&sA0[i4];
        float4 v1a = *(const float4*)&sA1[i4];
        float wdv[4] = {wd.x, wd.y, wd.z, wd.w};
        float wav[4] = {wa.x, wa.y, wa.z, wa.w};
        float s0d[4] = {v0d.x, v0d.y, v0d.z, v0d.w};
        float s1d[4] = {v1d.x, v1d.y, v1d.z, v1d.w};
        float s0a[4] = {v0a.x, v0a.y, v0a.z, v0a.w};
        float s1a[4] = {v1a.x, v1a.y, v1a.z, v1a.w};
#pragma unroll
        for (int j = 0; j < 4; ++j) {
            float2 td = *(const float2*)&tdT[(long)(i4 + j) * TT + tt0];
            float2 ta = *(const float2*)&taT[(long)(i4 + j) * TT + tt0];
            adc00 = fmaf(fmaxf(td.x + s0d[j], 0.0f), wdv[j], adc00);
            adc01 = fmaf(fmaxf(td.y + s0d[j], 0.0f), wdv[j], adc01);
            adc10 = fmaf(fmaxf(td.x + s1d[j], 0.0f), wdv[j], adc10);
            adc11 = fmaf(fmaxf(td.y + s1d[j], 0.0f), wdv[j], adc11);
            aA00 = fmaf(fmaxf(ta.x + s0a[j], 0.0f), wav[j], aA00);
            aA01 = fmaf(fmaxf(ta.y + s0a[j], 0.0f), wav[j], aA01);
            aA10 = fmaf(fmaxf(ta.x + s1a[j], 0.0f), wav[j], aA10);
            aA11 = fmaf(fmaxf(ta.y + s1a[j], 0.0f), wav[j], aA11);
        }
    }
    // ---- energies (all inputs already in registers) ----
    float p0 = 0.0f, p1 = 0.0f, p2 = 0.0f, p3 = 0.0f;
#pragma unroll
    for (int jj = 0; jj < 2; ++jj) {
        float tx = jj ? tx1 : tx0, ty = jj ? ty1 : ty0, tz = jj ? tz1 : tz0;
        float tr = jj ? tr1 : tr0, tv = jj ? tv1 : tv0;
#pragma unroll
        for (int li = 0; li < 2; ++li) {
            float dx = (li ? lx1 : lx0) - tx;
            float dy = (li ? ly1 : ly0) - ty;
            float dz = (li ? lz1 : lz0) - tz;
            float dm = sqrtf(dx * dx + dy * dy + dz * dz + 1e-10f);
            if (dm < 0.5f) dm = 1e10f;
            float adcv = jj ? (li ? adc11 : adc01) : (li ? adc10 : adc00);
            float aAv  = jj ? (li ? aA11  : aA01)  : (li ? aA10  : aA00);
            float dev = tanhf(adcv + cdcb2) * 0.2f;
            float vdws = (li ? lr1 : lr0) + tr + dev;
            float dm0 = (vdws < 1e-4f) ? 1.0f : vdws;
            float ratio = dm0 / dm;
            float r2 = ratio * ratio, r6 = r2 * r2 * r2, r12 = r6 * r6;
            float en = fminf(r12 - 2.0f * r6, 100.0f) * (li ? lv1 : lv0) * tv;
            float As = 1.0f / (1.0f + expf(-(aAv + cab2)));
            As = As * (0.0356f - 0.0178f) + 0.0178f;
            p0 = fmaf(As, en, p0);
            float dd = dm - vdws;
            float ramp = fminf(fmaxf(dd * (1.0f / -0.7f), 0.0f), 1.0f);
            float ramp2 = fminf(fmaxf(-dd + 1.5f, 0.0f), 1.0f);
            float vA = jj ? (li ? iA11 : iA01) : (li ? iA10 : iA00);
            float vB = jj ? (li ? iB11 : iB01) : (li ? iB10 : iB00);
            float vC = jj ? (li ? iC11 : iC01) : (li ? iC10 : iC00);
            p1 = fmaf(ramp, vA, p1);
            p2 = fmaf(ramp, vB, p2);
            p3 = fmaf(ramp2, vC, p3);
        }
    }
    // ---- reduction: wave shfl -> 4x4 LDS -> atomics (2 barriers total) ----
#pragma unroll
    for (int s = 32; s > 0; s >>= 1) {
        p0 += __shfl_xor(p0, s);
        p1 += __shfl_xor(p1, s);
        p2 += __shfl_xor(p2, s);
        p3 += __shfl_xor(p3, s);
    }
    int w = t >> 6, lane = t & 63;
    if (lane == 0) { redw[w][0] = p0; redw[w][1] = p1; redw[w][2] = p2; redw[w][3] = p3; }
    __syncthreads();
    if (t < 4) {
        float v = redw[0][t] + redw[1][t] + redw[2][t] + redw[3][t];
        atomicAdd(&accum[b * 4 + t], v);
    }
}

__global__ void finalize(const float* __restrict__ accum, const void* __restrict__ hb,
                         const void* __restrict__ mc, const void* __restrict__ hyd,
                         const void* __restrict__ rc, const void* __restrict__ rotor,
                         void* __restrict__ out, const int* __restrict__ flagp) {
    int bf = *flagp;
    int t = threadIdx.x;  // 64 threads, use first 32
    if (t >= 32) return;
    int b = t >> 2, e = t & 3;
    float v = accum[t];
    if (e == 1) { float c = LD(hb, 0, bf);  v = -c * c * v; }
    else if (e == 2) { float c = LD(mc, 0, bf);  v = -c * c * v; }
    else if (e == 3) { float c = LD(hyd, 0, bf); v = -c * c * v; }
    float r = LD(rc, 0, bf);
    float den = 1.0f + r * r * LD(rotor, b, bf);
    float res = v / den;
    if (bf) ((bf16*)out)[t] = __float2bfloat16(res);
    else    ((float*)out)[t] = res;
}

extern "C" void kernel_launch(void* const* d_in, const int* in_sizes, int n_in,
                              void* d_out, int out_size, void* d_ws, size_t ws_size,
                              hipStream_t stream) {
    const void* ligand_h = d_in[0];
    const void* target_h = d_in[1];
    const void* ligand_adj = d_in[2];
    const void* target_adj = d_in[3];
    const void* interaction_indice = d_in[4];
    const void* ligand_pos = d_in[5];
    const void* target_pos = d_in[6];
    const void* rotor = d_in[7];
    const void* ligand_vdw = d_in[8];
    const void* target_vdw = d_in[9];
    const void* ligand_valid = d_in[10];
    const void* target_valid = d_in[11];
    const void* emb_W = d_in[12];
    const void* gat_W = d_in[13];
    const void* gat_Wb = d_in[14];
    const void* gat_A = d_in[15];
    const void* gat_gW = d_in[16];
    const void* gat_gb = d_in[17];
    const void* vdwA_W1 = d_in[18];
    const void* vdwA_b1 = d_in[19];
    const void* vdwA_W2 = d_in[20];
    const void* vdwA_b2 = d_in[21];
    const void* dc_W1 = d_in[22];
    const void* dc_b1 = d_in[23];
    const void* dc_W2 = d_in[24];
    const void* dc_b2 = d_in[25];
    const void* hbond_coeff = d_in[26];
    const void* metal_coeff = d_in[27];
    const void* hydrophobic_coeff = d_in[28];
    const void* rotor_coeff = d_in[29];

    float* ws = (float*)d_ws;
    size_t off = 0;
    float* lig_x = ws + off;  off += (size_t)BB * LL * DIMD;   // x unified (lig, tgt)
    float* tgt_x = ws + off;  off += (size_t)BB * TT * DIMD;
    float* h_lig = ws + off;  off += (size_t)BB * LL * DIMD;   // h unified
    float* h_tgt = ws + off;  off += (size_t)BB * TT * DIMD;
    float* hA_lig = ws + off; off += (size_t)BB * LL * DIMD;   // hA unified (= P0)
    float* hA_tgt = ws + off; off += (size_t)BB * TT * DIMD;
    float* accum = ws + off;  off += 32;
    int* flagp = (int*)(ws + off); off += 2;
    float* e_buf = ws + off;  off += (size_t)BB * TT * TT;     // e target; later transposes
    float* e_lig = ws + off;  off += (size_t)BB * LL * LL;     // e ligand
    float* part1 = ws + off;  off += (size_t)BB * (LL + TT) * DIMD; // P1 unified
    float* projA = ws + off;  off += (size_t)BB * (LL + TT) * DIMD; // vdwA projection out
    float* cvw   = ws + off;  off += (size_t)CV_TOTAL;         // f32 weight copies
    float* part0 = hA_lig;       // P0 aliases hA (lig then tgt contiguous)
    // pair-MLP projection outputs
    float* ligdc = h_lig;        // dc out reuses h region (rows: lig then tgt)
    float* tgtdc = h_tgt;
    float* ligA = projA;         // vdwA out in fresh buffer (P0 race avoidance)
    float* tgtA = projA + (size_t)BB * LL * DIMD;
    // transposed target projections reuse e_buf (dead after the GAT loop)
    float* tgtdcT = e_buf;
    float* tgtAT  = e_buf + (size_t)BB * DIMD * TT;
    float* wEmb = cvw + CV_EMBW;

    init_cvt<<<(CV_TOTAL + 255) / 256, 256, 0, stream>>>(
        (const unsigned int*)emb_W, emb_W, gat_W, gat_A, gat_Wb,
        gat_gW, gat_gb, dc_W1, vdwA_W1, cvw, accum, flagp);

    // embeddings: x = h @ emb_W (both sides, one launch; out rows contiguous)
    embed_both<<<BB * (LL + TT), DIMD, 0, stream>>>(ligand_h, target_h, wEmb, lig_x, 54, flagp);

    const long ROWSPLIT = (long)BB * LL;   // multiple of 4
    for (int i = 0; i < 3; ++i) {
        // [gate of layer i-1] + h = x@W+Wb ; hA = h@A   (both sides, one launch)
        gemm_hha_gate<<<BB * (LL + TT) / 4, 256, 0, stream>>>(
            lig_x, part0, part1, cvw, i, i > 0 ? 1 : 0, h_lig, hA_lig);
        // e (symmetric, upper tiles + mirror), both sides
        esym_both<<<dim3(TGT_TILES + LIG_TILES, BB), 256, 0, stream>>>(
            hA_tgt, h_tgt, e_buf, hA_lig, h_lig, e_lig);
        // fused softmax + hp partial GEMM (split-K=2)
        hp_sm_both<<<dim3(20, 2, BB), 256, 0, stream>>>(
            e_buf, h_tgt, target_adj, e_lig, h_lig, ligand_adj,
            part0, part1, flagp);
    }

    // final gate (layer 2) + both pair-MLP projections in one launch
    proj_gate<<<dim3(BB * (LL + TT) / 4, 2), 256, 0, stream>>>(
        lig_x, part0, part1, cvw, dc_b1, vdwA_b1, ROWSPLIT, ligdc, ligA, flagp);

    // transpose target projections for coalesced pair_energy reads (one launch)
    transpose_both<<<dim3(TT / 32, DIMD / 32, 2 * BB), 256, 0, stream>>>(
        tgtdc, tgtdcT, tgtA, tgtAT);

    pair_energy<<<dim3(LL / 2, BB), 256, 0, stream>>>(
        ligdc, tgtdcT, ligA, tgtAT, dc_W2, dc_b2, vdwA_W2, vdwA_b2,
        ligand_pos, target_pos, ligand_vdw, target_vdw,
        ligand_valid, target_valid, interaction_indice, accum, flagp);

    finalize<<<1, 64, 0, stream>>>(accum, hbond_coeff, metal_coeff,
                                   hydrophobic_coeff, rotor_coeff, rotor, d_out, flagp);
}

// Round 11
// 373.312 us; speedup vs baseline: 1.1544x; 1.1544x over previous
//
#include <hip/hip_runtime.h>
#include <hip/hip_bf16.h>
#include <math.h>

typedef __hip_bfloat16 bf16;

#define DIMD 128
#define BB 8
#define LL 128
#define TT 512

// esym tile params
#define BMT 64
#define BKT 32
#define TGT_TILES 36   // 8*9/2 upper-tri tiles (N=512 / 64)
#define LIG_TILES 3    // 2*3/2 upper-tri tiles (N=128 / 64)

// cvt'd f32 weight region element offsets
#define CV_EMBW   0L
#define CV_GATW   (CV_EMBW + 54 * 128)
#define CV_GATA   (CV_GATW + 3 * 128 * 128)
#define CV_WB     (CV_GATA + 3 * 128 * 128)
#define CV_GGW    (CV_WB + 3 * 128)
#define CV_GGB    (CV_GGW + 3 * 2 * 128)
#define CV_DCW1   (CV_GGB + 4)
#define CV_VW1    (CV_DCW1 + 2 * 128 * 128)
#define CV_TOTAL  (CV_VW1 + 2 * 128 * 128)

// Runtime-dtype load of external inputs: bf==1 -> bf16, else f32.
__device__ __forceinline__ float LD(const void* p, long i, int bf) {
    if (bf) return __bfloat162float(((const bf16*)p)[i]);
    return ((const float*)p)[i];
}

// One-time: detect dtype (self-detect per block), zero accum, publish flagp,
// convert hot weights to f32 (branch-free GEMMs afterwards).
__global__ void init_cvt(const unsigned int* __restrict__ embw_raw,
                         const void* __restrict__ embW, const void* __restrict__ gatW,
                         const void* __restrict__ gatA, const void* __restrict__ gatWb,
                         const void* __restrict__ ggW, const void* __restrict__ ggb,
                         const void* __restrict__ dcW1, const void* __restrict__ vW1,
                         float* __restrict__ out, float* __restrict__ accum,
                         int* __restrict__ flagp) {
    __shared__ int cnts;
    int t = threadIdx.x;
    if (t == 0) cnts = 0;
    __syncthreads();
    unsigned int bword = (embw_raw[t] >> 8) & 0xffu;
    unsigned int e = bword & 0x7fu;
    if (e >= 0x38u && e <= 0x3fu) atomicAdd(&cnts, 1);
    __syncthreads();
    int bf = cnts > 128;
    if (blockIdx.x == 0) {
        if (t < 32) accum[t] = 0.0f;
        if (t == 0) *flagp = bf;
    }
    long i = (long)blockIdx.x * 256 + t;
    if (i >= CV_TOTAL) return;
    float v;
    if (i < CV_GATW)      v = LD(embW, i, bf);
    else if (i < CV_GATA) v = LD(gatW, i - CV_GATW, bf);
    else if (i < CV_WB)   v = LD(gatA, i - CV_GATA, bf);
    else if (i < CV_GGW)  v = LD(gatWb, i - CV_WB, bf);
    else if (i < CV_GGB)  v = LD(ggW, i - CV_GGW, bf);
    else if (i < CV_DCW1) { long j = i - CV_GGB; v = (j < 3) ? LD(ggb, j, bf) : 0.0f; }
    else if (i < CV_VW1)  v = LD(dcW1, i - CV_DCW1, bf);
    else                  v = LD(vW1, i - CV_VW1, bf);
    out[i] = v;
}

// Both-sides embedding: rows [0, BB*LL) from Xl, rest from Xt. K=54. f32 W.
__global__ void embed_both(const void* __restrict__ Xl, const void* __restrict__ Xt,
                           const float* __restrict__ Wf, float* __restrict__ out,
                           int K, const int* __restrict__ flagp) {
    __shared__ float xrow[DIMD];
    int bf = *flagp;
    int row = blockIdx.x;
    int d = threadIdx.x;
    const void* X; long r;
    if (row < BB * LL) { X = Xl; r = row; }
    else               { X = Xt; r = row - BB * LL; }
    if (d < K) xrow[d] = LD(X, r * K + d, bf);
    __syncthreads();
    float acc = 0.0f;
    for (int k = 0; k < K; ++k)
        acc = fmaf(xrow[k], Wf[(long)k * DIMD + d], acc);
    out[(long)row * DIMD + d] = acc;
}

// Fused [gate of previous layer] + h = x@W + Wb + hA = h@A.
// 4 rows/block, 256 threads, ILP-4 k-loops (two 64-halves per chain).
// P0..P3 = split-K hp partials of previous layer (unified row space).
// P0 aliases hA: each block reads its own rows before rewriting them.
__global__ void gemm_hha_gate(float* __restrict__ X, const float* __restrict__ P0,
                              const float* __restrict__ P1, const float* __restrict__ P2,
                              const float* __restrict__ P3, const float* __restrict__ cvw,
                              int layer, int dogate,
                              float* __restrict__ hout, float* __restrict__ hAout) {
    __shared__ float xs[4][DIMD];
    __shared__ float hs[4][DIMD];
    __shared__ float gred[4][2];
    long row0 = (long)blockIdx.x * 4;
    int d = threadIdx.x & 127, rg = threadIdx.x >> 7;
    int w = threadIdx.x >> 6, lane = threadIdx.x & 63;
    long r0 = row0 + rg * 2, r1 = r0 + 1;
    float xv0 = X[r0 * DIMD + d];
    float xv1 = X[r1 * DIMD + d];
    if (dogate) {
        const float* gW = cvw + CV_GGW + (long)(layer - 1) * 2 * DIMD;
        float gb = cvw[CV_GGB + (layer - 1)];
        float hp0 = fmaxf(P0[r0 * DIMD + d] + P1[r0 * DIMD + d]
                        + P2[r0 * DIMD + d] + P3[r0 * DIMD + d], 0.0f);
        float hp1 = fmaxf(P0[r1 * DIMD + d] + P1[r1 * DIMD + d]
                        + P2[r1 * DIMD + d] + P3[r1 * DIMD + d], 0.0f);
        float s0 = xv0 * gW[d] + hp0 * gW[DIMD + d];
        float s1 = xv1 * gW[d] + hp1 * gW[DIMD + d];
#pragma unroll
        for (int s = 32; s > 0; s >>= 1) { s0 += __shfl_xor(s0, s); s1 += __shfl_xor(s1, s); }
        if (lane == 0) { gred[rg * 2 + 0][w & 1] = s0; gred[rg * 2 + 1][w & 1] = s1; }
        __syncthreads();
        float g0 = gred[rg * 2 + 0][0] + gred[rg * 2 + 0][1] + gb;
        float g1 = gred[rg * 2 + 1][0] + gred[rg * 2 + 1][1] + gb;
        float c0 = 1.0f / (1.0f + expf(-g0));
        float c1 = 1.0f / (1.0f + expf(-g1));
        xv0 = c0 * xv0 + (1.0f - c0) * hp0;
        xv1 = c1 * xv1 + (1.0f - c1) * hp1;
        X[r0 * DIMD + d] = xv0;   // gated x for the next consumer
        X[r1 * DIMD + d] = xv1;
    }
    xs[rg * 2 + 0][d] = xv0;
    xs[rg * 2 + 1][d] = xv1;
    __syncthreads();
    const float* W = cvw + CV_GATW + (long)layer * DIMD * DIMD;
    const float* A = cvw + CV_GATA + (long)layer * DIMD * DIMD;
    float b = cvw[CV_WB + layer * DIMD + d];
    const float* x0 = xs[rg * 2];
    const float* x1 = xs[rg * 2 + 1];
    float h0a = b, h0b = 0.0f, h1a = b, h1b = 0.0f;
#pragma unroll 4
    for (int k = 0; k < 64; ++k) {
        float w0 = W[(long)k * DIMD + d];
        float w1 = W[(long)(k + 64) * DIMD + d];
        h0a = fmaf(x0[k], w0, h0a);
        h0b = fmaf(x0[k + 64], w1, h0b);
        h1a = fmaf(x1[k], w0, h1a);
        h1b = fmaf(x1[k + 64], w1, h1b);
    }
    float h0 = h0a + h0b, h1 = h1a + h1b;
    long ob = r0 * DIMD + d;
    hout[ob] = h0; hout[ob + DIMD] = h1;
    hs[rg * 2][d] = h0; hs[rg * 2 + 1][d] = h1;
    __syncthreads();
    const float* g0p = hs[rg * 2];
    const float* g1p = hs[rg * 2 + 1];
    float a0a = 0.0f, a0b = 0.0f, a1a = 0.0f, a1b = 0.0f;
#pragma unroll 4
    for (int k = 0; k < 64; ++k) {
        float w0 = A[(long)k * DIMD + d];
        float w1 = A[(long)(k + 64) * DIMD + d];
        a0a = fmaf(g0p[k], w0, a0a);
        a0b = fmaf(g0p[k + 64], w1, a0b);
        a1a = fmaf(g1p[k], w0, a1a);
        a1b = fmaf(g1p[k + 64], w1, a1b);
    }
    hAout[ob] = a0a + a0b;
    hAout[ob + DIMD] = a1a + a1b;
}

// e = S1 + S2, S1 = hA·h^T, S2 = h·hA^T (each symmetric-pair-mirrorable).
// blockIdx.y selects the term. Upper-triangle tiles + mirror writes.
__global__ void esym_both(const float* __restrict__ hA_t, const float* __restrict__ h_t,
                          float* __restrict__ e1_t, float* __restrict__ e2_t,
                          const float* __restrict__ hA_l, const float* __restrict__ h_l,
                          float* __restrict__ e1_l, float* __restrict__ e2_l) {
    __shared__ float At[BKT][BMT + 4];
    __shared__ float Bt[BKT][BMT + 4];
    int idx = blockIdx.x, half = blockIdx.y, b = blockIdx.z, t = threadIdx.x;
    const float *hA, *h; float* e; int N;
    if (idx < TGT_TILES) { hA = hA_t; h = h_t; e = half ? e2_t : e1_t; N = TT; }
    else { idx -= TGT_TILES; hA = hA_l; h = h_l; e = half ? e2_l : e1_l; N = LL; }
    int jt = (int)((sqrtf(8.0f * idx + 1.0f) - 1.0f) * 0.5f);
    while ((jt + 1) * (jt + 2) / 2 <= idx) ++jt;
    while (jt * (jt + 1) / 2 > idx) --jt;
    int kt = idx - jt * (jt + 1) / 2;   // kt <= jt
    const float* hAb = hA + (long)b * N * DIMD;
    const float* hb  = h  + (long)b * N * DIMD;
    const float* Ap = half ? hb : hAb;
    const float* Bp = half ? hAb : hb;
    int tm = t & 15, tn = t >> 4;
    int k4 = (t & 7) * 4;
    int row0 = t >> 3;
    float acc[4][4];
#pragma unroll
    for (int i = 0; i < 4; ++i)
#pragma unroll
        for (int jj = 0; jj < 4; ++jj) acc[i][jj] = 0.0f;

#pragma unroll
    for (int c = 0; c < 4; ++c) {
        int ko = c * BKT;
        __syncthreads();
#pragma unroll
        for (int rr = 0; rr < 2; ++rr) {
            int row = row0 + rr * 32;
            float4 av = *(const float4*)&Ap[(long)(jt * BMT + row) * DIMD + ko + k4];
            float4 bv = *(const float4*)&Bp[(long)(kt * BMT + row) * DIMD + ko + k4];
            At[k4 + 0][row] = av.x; At[k4 + 1][row] = av.y;
            At[k4 + 2][row] = av.z; At[k4 + 3][row] = av.w;
            Bt[k4 + 0][row] = bv.x; Bt[k4 + 1][row] = bv.y;
            Bt[k4 + 2][row] = bv.z; Bt[k4 + 3][row] = bv.w;
        }
        __syncthreads();
#pragma unroll
        for (int k = 0; k < BKT; ++k) {
            float4 a4 = *(const float4*)&At[k][tm * 4];
            float4 b4 = *(const float4*)&Bt[k][tn * 4];
            float A[4] = {a4.x, a4.y, a4.z, a4.w};
            float Bv[4] = {b4.x, b4.y, b4.z, b4.w};
#pragma unroll
            for (int i = 0; i < 4; ++i)
#pragma unroll
                for (int jj = 0; jj < 4; ++jj)
                    acc[i][jj] = fmaf(A[i], Bv[jj], acc[i][jj]);
        }
    }
    long ebN = (long)b * N;
    long ebase = (ebN + jt * BMT + tm * 4) * N + kt * BMT + tn * 4;
#pragma unroll
    for (int i = 0; i < 4; ++i) {
        float4 v;
        v.x = acc[i][0]; v.y = acc[i][1]; v.z = acc[i][2]; v.w = acc[i][3];
        *(float4*)&e[ebase + (long)i * N] = v;
    }
    if (jt != kt) {   // mirror (transpose) — sum of halves stays symmetric
        long mbase = (ebN + kt * BMT + tn * 4) * N + jt * BMT + tm * 4;
#pragma unroll
        for (int jj = 0; jj < 4; ++jj) {
            float4 v;
            v.x = acc[0][jj]; v.y = acc[1][jj]; v.z = acc[2][jj]; v.w = acc[3][jj];
            *(float4*)&e[mbase + (long)jj * N] = v;
        }
    }
}

// att row softmax, one WAVE per row. Reads e1+e2, writes normalized att to e1.
template<int CNT>
__device__ __forceinline__ void softmax_row(float* __restrict__ e1row,
                                            const float* __restrict__ e2row,
                                            const void* __restrict__ adj,
                                            long adjbase, int bf) {
    int lane = threadIdx.x & 63;
    float vals[CNT], av[CNT];
    float m = -3.4e38f;
#pragma unroll
    for (int i = 0; i < CNT; ++i) {
        int k = lane + i * 64;
        float a = LD(adj, adjbase + k, bf);
        float v = (a > 0.0f) ? (e1row[k] + e2row[k]) : -9e15f;
        av[i] = a; vals[i] = v;
        m = fmaxf(m, v);
    }
#pragma unroll
    for (int s = 32; s > 0; s >>= 1) m = fmaxf(m, __shfl_xor(m, s));
    float sum = 0.0f;
#pragma unroll
    for (int i = 0; i < CNT; ++i) { vals[i] = expf(vals[i] - m); sum += vals[i]; }
#pragma unroll
    for (int s = 32; s > 0; s >>= 1) sum += __shfl_xor(sum, s);
    float inv = 1.0f / sum;
#pragma unroll
    for (int i = 0; i < CNT; ++i)
        e1row[lane + i * 64] = vals[i] * av[i] * inv;
}

// x < TT/4: target rows; else ligand rows. 4 waves = 4 rows per block.
__global__ void att_softmax_both(float* __restrict__ e1_t, const float* __restrict__ e2_t,
                                 float* __restrict__ e1_l, const float* __restrict__ e2_l,
                                 const void* __restrict__ adj_t, const void* __restrict__ adj_l,
                                 const int* __restrict__ flagp) {
    int bf = *flagp;
    int b = blockIdx.y, x = blockIdx.x;
    int jr = threadIdx.x >> 6;
    if (x < TT / 4) {
        int j = x * 4 + jr;
        long base = ((long)b * TT + j) * TT;
        softmax_row<8>(e1_t + base, e2_t + base, adj_t, base, bf);
    } else {
        int j = (x - TT / 4) * 4 + jr;
        long base = ((long)b * LL + j) * LL;
        softmax_row<2>(e1_l + base, e2_l + base, adj_l, base, bf);
    }
}

// Partial hp GEMM: P[kc][row][d] = sum over k-quarter of att[j][k]*h[k][d]
// BM=32, BN=128, BK=32, 256 threads, 4x4 acc, split-K=4 via blockIdx.y.
// Register double-buffer for At/Ht staging (prefetch next tile pre-barrier).
// Grid x: [0,16) target row-tiles, [16,20) ligand row-tiles.
// P0..P3 are UNIFIED row-space bases (lig rows first, then tgt).
__global__ void hp_gemm_both(const float* __restrict__ att_t, const float* __restrict__ h_t,
                             const float* __restrict__ att_l, const float* __restrict__ h_l,
                             float* __restrict__ P0, float* __restrict__ P1,
                             float* __restrict__ P2, float* __restrict__ P3) {
    __shared__ float At[32][36];
    __shared__ float Ht[32][DIMD];
    int jt = blockIdx.x, kc = blockIdx.y, b = blockIdx.z;
    int t = threadIdx.x;
    const float *att, *h; int N; long rowbase;
    if (jt < 16) { att = att_t; h = h_t; N = TT; rowbase = (long)BB * LL + (long)b * TT; }
    else { jt -= 16; att = att_l; h = h_l; N = LL; rowbase = (long)b * LL; }
    const float* attb = att + (long)b * N * N;
    const float* hb = h + (long)b * N * DIMD;
    int tm = t & 7, tn = t >> 3;
    float acc[4][4] = {};
    int kchunk = N / 4;
    int kbeg = kc * kchunk;
    int kend = kbeg + kchunk;
    int ar = t >> 3;
    int ac4 = (t & 7) * 4;
    int hk = t >> 5;
    int hc4 = (t & 31) * 4;
    // prefetch first tile
    float4 avp = *(const float4*)&attb[(long)(jt * 32 + ar) * N + kbeg + ac4];
    float4 hp[4];
#pragma unroll
    for (int p = 0; p < 4; ++p)
        hp[p] = *(const float4*)&hb[(long)(kbeg + hk + p * 8) * DIMD + hc4];
    for (int k0 = kbeg; k0 < kend; k0 += 32) {
        __syncthreads();   // previous tile's compute done
        At[ac4 + 0][ar] = avp.x; At[ac4 + 1][ar] = avp.y;
        At[ac4 + 2][ar] = avp.z; At[ac4 + 3][ar] = avp.w;
#pragma unroll
        for (int p = 0; p < 4; ++p) *(float4*)&Ht[hk + p * 8][hc4] = hp[p];
        if (k0 + 32 < kend) {   // prefetch next tile (overlaps with compute)
            avp = *(const float4*)&attb[(long)(jt * 32 + ar) * N + k0 + 32 + ac4];
#pragma unroll
            for (int p = 0; p < 4; ++p)
                hp[p] = *(const float4*)&hb[(long)(k0 + 32 + hk + p * 8) * DIMD + hc4];
        }
        __syncthreads();
#pragma unroll
        for (int k = 0; k < 32; ++k) {
            float4 a4 = *(const float4*)&At[k][tm * 4];
            float4 h4 = *(const float4*)&Ht[k][tn * 4];
            float A[4] = {a4.x, a4.y, a4.z, a4.w};
            float H[4] = {h4.x, h4.y, h4.z, h4.w};
#pragma unroll
            for (int i = 0; i < 4; ++i)
#pragma unroll
                for (int jj = 0; jj < 4; ++jj)
                    acc[i][jj] = fmaf(A[i], H[jj], acc[i][jj]);
        }
    }
    float* outp = (kc == 0) ? P0 : (kc == 1) ? P1 : (kc == 2) ? P2 : P3;
    long obase = (rowbase + jt * 32 + tm * 4) * DIMD + tn * 4;
#pragma unroll
    for (int i = 0; i < 4; ++i) {
        float4 v; v.x = acc[i][0]; v.y = acc[i][1]; v.z = acc[i][2]; v.w = acc[i][3];
        *(float4*)&outp[obase + (long)i * DIMD] = v;
    }
}

// Final-layer gate + both pair-MLP projections. blockIdx.y: 0=dc, 1=vdwA.
__global__ void proj_gate(const float* __restrict__ X, const float* __restrict__ P0,
                          const float* __restrict__ P1, const float* __restrict__ P2,
                          const float* __restrict__ P3, const float* __restrict__ cvw,
                          const void* __restrict__ bdc, const void* __restrict__ bA,
                          long rowsplit, float* __restrict__ outdc, float* __restrict__ outA,
                          const int* __restrict__ flagp) {
    __shared__ float xs[4][DIMD];
    __shared__ float gred[4][2];
    int bf = *flagp;
    long row0 = (long)blockIdx.x * 4;
    int d = threadIdx.x & 127, rg = threadIdx.x >> 7;
    int w = threadIdx.x >> 6, lane = threadIdx.x & 63;
    long r0 = row0 + rg * 2, r1 = r0 + 1;
    float xv0 = X[r0 * DIMD + d];
    float xv1 = X[r1 * DIMD + d];
    {
        const float* gW = cvw + CV_GGW + 2L * 2 * DIMD;
        float gb = cvw[CV_GGB + 2];
        float hp0 = fmaxf(P0[r0 * DIMD + d] + P1[r0 * DIMD + d]
                        + P2[r0 * DIMD + d] + P3[r0 * DIMD + d], 0.0f);
        float hp1 = fmaxf(P0[r1 * DIMD + d] + P1[r1 * DIMD + d]
                        + P2[r1 * DIMD + d] + P3[r1 * DIMD + d], 0.0f);
        float s0 = xv0 * gW[d] + hp0 * gW[DIMD + d];
        float s1 = xv1 * gW[d] + hp1 * gW[DIMD + d];
#pragma unroll
        for (int s = 32; s > 0; s >>= 1) { s0 += __shfl_xor(s0, s); s1 += __shfl_xor(s1, s); }
        if (lane == 0) { gred[rg * 2 + 0][w & 1] = s0; gred[rg * 2 + 1][w & 1] = s1; }
        __syncthreads();
        float g0 = gred[rg * 2 + 0][0] + gred[rg * 2 + 0][1] + gb;
        float g1 = gred[rg * 2 + 1][0] + gred[rg * 2 + 1][1] + gb;
        float c0 = 1.0f / (1.0f + expf(-g0));
        float c1 = 1.0f / (1.0f + expf(-g1));
        xv0 = c0 * xv0 + (1.0f - c0) * hp0;
        xv1 = c1 * xv1 + (1.0f - c1) * hp1;
    }
    xs[rg * 2 + 0][d] = xv0;
    xs[rg * 2 + 1][d] = xv1;
    __syncthreads();
    const float* Wf = (blockIdx.y == 0) ? (cvw + CV_DCW1) : (cvw + CV_VW1);
    const void* bias = (blockIdx.y == 0) ? bdc : bA;
    float* out = (blockIdx.y == 0) ? outdc : outA;
    int sideb = row0 >= rowsplit;
    const float* W = Wf + (sideb ? (long)DIMD * DIMD : 0);
    float b0 = sideb ? 0.0f : LD(bias, d, bf);
    const float* x0 = xs[rg * 2];
    const float* x1 = xs[rg * 2 + 1];
    float a0a = b0, a0b = 0.0f, a1a = b0, a1b = 0.0f;
#pragma unroll 4
    for (int k = 0; k < 64; ++k) {
        float w0 = W[(long)k * DIMD + d];
        float w1 = W[(long)(k + 64) * DIMD + d];
        a0a = fmaf(x0[k], w0, a0a);
        a0b = fmaf(x0[k + 64], w1, a0b);
        a1a = fmaf(x1[k], w0, a1a);
        a1b = fmaf(x1[k + 64], w1, a1b);
    }
    long ob = r0 * DIMD + d;
    out[ob] = a0a + a0b;
    out[ob + DIMD] = a1a + a1b;
}

// Both transposes in one launch: z<BB -> (in0->out0, b=z), else (in1->out1).
__global__ void transpose_both(const float* __restrict__ in0, float* __restrict__ out0,
                               const float* __restrict__ in1, float* __restrict__ out1) {
    __shared__ float tile[32][33];
    int z = blockIdx.z;
    const float* in; float* outT; int b;
    if (z < BB) { in = in0; outT = out0; b = z; }
    else        { in = in1; outT = out1; b = z - BB; }
    int n0 = blockIdx.x * 32;
    int d0 = blockIdx.y * 32;
    int t = threadIdx.x;
    int tx = t & 31, ty = t >> 5;
    for (int r = ty; r < 32; r += 8)
        tile[r][tx] = in[((long)b * TT + n0 + r) * DIMD + d0 + tx];
    __syncthreads();
    for (int r = ty; r < 32; r += 8)
        outT[((long)b * DIMD + d0 + r) * TT + n0 + tx] = tile[tx][r];
}

// Pair energies. Block = (b, 2 ligand rows); lane handles tt = 2t, 2t+1.
// All end-phase scalars (tpos/trad/tval/ii) PREFETCHED before the dot loop so
// their HBM latency hides under the 128-iter L2-bound MLP dot phase.
__global__ void pair_energy(const float* __restrict__ ligdc, const float* __restrict__ tgtdcT,
                            const float* __restrict__ ligA, const float* __restrict__ tgtAT,
                            const void* __restrict__ dcW2, const void* __restrict__ dcb2,
                            const void* __restrict__ AW2, const void* __restrict__ Ab2,
                            const void* __restrict__ lpos, const void* __restrict__ tpos,
                            const void* __restrict__ lrad, const void* __restrict__ trad,
                            const void* __restrict__ lval, const void* __restrict__ tval,
                            const void* __restrict__ ii, float* __restrict__ accum,
                            const int* __restrict__ flagp) {
    int bf = *flagp;
    int l0 = blockIdx.x * 2, b = blockIdx.y, t = threadIdx.x;
    __shared__ __align__(16) float sdc0[DIMD], sdc1[DIMD], sA0[DIMD], sA1[DIMD];
    __shared__ __align__(16) float w2dc[DIMD], w2A[DIMD];
    __shared__ float redw[4][4];
    if (t < DIMD) {
        sdc0[t] = ligdc[((long)b * LL + l0) * DIMD + t];
        sA0[t]  = ligA [((long)b * LL + l0) * DIMD + t];
        w2dc[t] = LD(dcW2, t, bf);
        w2A[t]  = LD(AW2, t, bf);
    } else {
        int u = t - DIMD;
        sdc1[u] = ligdc[((long)b * LL + l0 + 1) * DIMD + u];
        sA1[u]  = ligA [((long)b * LL + l0 + 1) * DIMD + u];
    }
    int tt0 = t * 2;
    // ---- prefetch (issued before the dot loop; consumed after it) ----
    float tx0 = LD(tpos, ((long)b * TT + tt0) * 3 + 0, bf);
    float ty0 = LD(tpos, ((long)b * TT + tt0) * 3 + 1, bf);
    float tz0 = LD(tpos, ((long)b * TT + tt0) * 3 + 2, bf);
    float tx1 = LD(tpos, ((long)b * TT + tt0 + 1) * 3 + 0, bf);
    float ty1 = LD(tpos, ((long)b * TT + tt0 + 1) * 3 + 1, bf);
    float tz1 = LD(tpos, ((long)b * TT + tt0 + 1) * 3 + 2, bf);
    float tr0 = LD(trad, (long)b * TT + tt0, bf);
    float tr1 = LD(trad, (long)b * TT + tt0 + 1, bf);
    float tv0 = LD(tval, (long)b * TT + tt0, bf);
    float tv1 = LD(tval, (long)b * TT + tt0 + 1, bf);
    long iiA0 = ((long)(b * 3 + 0) * LL + l0) * TT;
    long iiB0 = ((long)(b * 3 + 1) * LL + l0) * TT;
    long iiC0 = ((long)(b * 3 + 2) * LL + l0) * TT;
    long iiA1 = iiA0 + TT, iiB1 = iiB0 + TT, iiC1 = iiC0 + TT;
    float iA00 = LD(ii, iiA0 + tt0, bf), iA01 = LD(ii, iiA0 + tt0 + 1, bf);
    float iA10 = LD(ii, iiA1 + tt0, bf), iA11 = LD(ii, iiA1 + tt0 + 1, bf);
    float iB00 = LD(ii, iiB0 + tt0, bf), iB01 = LD(ii, iiB0 + tt0 + 1, bf);
    float iB10 = LD(ii, iiB1 + tt0, bf), iB11 = LD(ii, iiB1 + tt0 + 1, bf);
    float iC00 = LD(ii, iiC0 + tt0, bf), iC01 = LD(ii, iiC0 + tt0 + 1, bf);
    float iC10 = LD(ii, iiC1 + tt0, bf), iC11 = LD(ii, iiC1 + tt0 + 1, bf);
    float lx0 = LD(lpos, ((long)b * LL + l0) * 3 + 0, bf);
    float ly0 = LD(lpos, ((long)b * LL + l0) * 3 + 1, bf);
    float lz0 = LD(lpos, ((long)b * LL + l0) * 3 + 2, bf);
    float lx1 = LD(lpos, ((long)b * LL + l0 + 1) * 3 + 0, bf);
    float ly1 = LD(lpos, ((long)b * LL + l0 + 1) * 3 + 1, bf);
    float lz1 = LD(lpos, ((long)b * LL + l0 + 1) * 3 + 2, bf);
    float lr0 = LD(lrad, (long)b * LL + l0, bf);
    float lr1 = LD(lrad, (long)b * LL + l0 + 1, bf);
    float lv0 = LD(lval, (long)b * LL + l0, bf);
    float lv1 = LD(lval, (long)b * LL + l0 + 1, bf);
    float cdcb2 = LD(dcb2, 0, bf), cab2 = LD(Ab2, 0, bf);
    __syncthreads();
    // ---- MLP dot loop (L2-bound; hides the prefetch latency) ----
    const float* tdT = tgtdcT + (long)b * DIMD * TT;
    const float* taT = tgtAT  + (long)b * DIMD * TT;
    float adc00 = 0.0f, adc01 = 0.0f, adc10 = 0.0f, adc11 = 0.0f;
    float aA00 = 0.0f, aA01 = 0.0f, aA10 = 0.0f, aA11 = 0.0f;
    for (int i4 = 0; i4 < DIMD; i4 += 4) {
        float4 wd = *(const float4*)&w2dc[i4];
        float4 wa = *(const float4*)&w2A[i4];
        float4 v0d = *(const float4*)&sdc0[i4];
        float4 v1d = *(const float4*)&sdc1[i4];
        float4 v0a = *(const float4*)&sA0[i4];
        float4 v1a = *(const float4*)&sA1[i4];
        float wdv[4] = {wd.x, wd.y, wd.z, wd.w};
        float wav[4] = {wa.x, wa.y, wa.z, wa.w};
        float s0d[4] = {v0d.x, v0d.y, v0d.z, v0d.w};
        float s1d[4] = {v1d.x, v1d.y, v1d.z, v1d.w};
        float s0a[4] = {v0a.x, v0a.y, v0a.z, v0a.w};
        float s1a[4] = {v1a.x, v1a.y, v1a.z, v1a.w};
#pragma unroll
        for (int j = 0; j < 4; ++j) {
            float2 td = *(const float2*)&tdT[(long)(i4 + j) * TT + tt0];
            float2 ta = *(const float2*)&taT[(long)(i4 + j) * TT + tt0];
            adc00 = fmaf(fmaxf(td.x + s0d[j], 0.0f), wdv[j], adc00);
            adc01 = fmaf(fmaxf(td.y + s0d[j], 0.0f), wdv[j], adc01);
            adc10 = fmaf(fmaxf(td.x + s1d[j], 0.0f), wdv[j], adc10);
            adc11 = fmaf(fmaxf(td.y + s1d[j], 0.0f), wdv[j], adc11);
            aA00 = fmaf(fmaxf(ta.x + s0a[j], 0.0f), wav[j], aA00);
            aA01 = fmaf(fmaxf(ta.y + s0a[j], 0.0f), wav[j], aA01);
            aA10 = fmaf(fmaxf(ta.x + s1a[j], 0.0f), wav[j], aA10);
            aA11 = fmaf(fmaxf(ta.y + s1a[j], 0.0f), wav[j], aA11);
        }
    }
    // ---- energies (all inputs already in registers) ----
    float p0 = 0.0f, p1 = 0.0f, p2 = 0.0f, p3 = 0.0f;
#pragma unroll
    for (int jj = 0; jj < 2; ++jj) {
        float tx = jj ? tx1 : tx0, ty = jj ? ty1 : ty0, tz = jj ? tz1 : tz0;
        float tr = jj ? tr1 : tr0, tv = jj ? tv1 : tv0;
#pragma unroll
        for (int li = 0; li < 2; ++li) {
            float dx = (li ? lx1 : lx0) - tx;
            float dy = (li ? ly1 : ly0) - ty;
            float dz = (li ? lz1 : lz0) - tz;
            float dm = sqrtf(dx * dx + dy * dy + dz * dz + 1e-10f);
            if (dm < 0.5f) dm = 1e10f;
            float adcv = jj ? (li ? adc11 : adc01) : (li ? adc10 : adc00);
            float aAv  = jj ? (li ? aA11  : aA01)  : (li ? aA10  : aA00);
            float dev = tanhf(adcv + cdcb2) * 0.2f;
            float vdws = (li ? lr1 : lr0) + tr + dev;
            float dm0 = (vdws < 1e-4f) ? 1.0f : vdws;
            float ratio = dm0 / dm;
            float r2 = ratio * ratio, r6 = r2 * r2 * r2, r12 = r6 * r6;
            float en = fminf(r12 - 2.0f * r6, 100.0f) * (li ? lv1 : lv0) * tv;
            float As = 1.0f / (1.0f + expf(-(aAv + cab2)));
            As = As * (0.0356f - 0.0178f) + 0.0178f;
            p0 = fmaf(As, en, p0);
            float dd = dm - vdws;
            float ramp = fminf(fmaxf(dd * (1.0f / -0.7f), 0.0f), 1.0f);
            float ramp2 = fminf(fmaxf(-dd + 1.5f, 0.0f), 1.0f);
            float vA = jj ? (li ? iA11 : iA01) : (li ? iA10 : iA00);
            float vB = jj ? (li ? iB11 : iB01) : (li ? iB10 : iB00);
            float vC = jj ? (li ? iC11 : iC01) : (li ? iC10 : iC00);
            p1 = fmaf(ramp, vA, p1);
            p2 = fmaf(ramp, vB, p2);
            p3 = fmaf(ramp2, vC, p3);
        }
    }
    // ---- reduction: wave shfl -> 4x4 LDS -> atomics (2 barriers total) ----
#pragma unroll
    for (int s = 32; s > 0; s >>= 1) {
        p0 += __shfl_xor(p0, s);
        p1 += __shfl_xor(p1, s);
        p2 += __shfl_xor(p2, s);
        p3 += __shfl_xor(p3, s);
    }
    int w = t >> 6, lane = t & 63;
    if (lane == 0) { redw[w][0] = p0; redw[w][1] = p1; redw[w][2] = p2; redw[w][3] = p3; }
    __syncthreads();
    if (t < 4) {
        float v = redw[0][t] + redw[1][t] + redw[2][t] + redw[3][t];
        atomicAdd(&accum[b * 4 + t], v);
    }
}

__global__ void finalize(const float* __restrict__ accum, const void* __restrict__ hb,
                         const void* __restrict__ mc, const void* __restrict__ hyd,
                         const void* __restrict__ rc, const void* __restrict__ rotor,
                         void* __restrict__ out, const int* __restrict__ flagp) {
    int bf = *flagp;
    int t = threadIdx.x;  // 64 threads, use first 32
    if (t >= 32) return;
    int b = t >> 2, e = t & 3;
    float v = accum[t];
    if (e == 1) { float c = LD(hb, 0, bf);  v = -c * c * v; }
    else if (e == 2) { float c = LD(mc, 0, bf);  v = -c * c * v; }
    else if (e == 3) { float c = LD(hyd, 0, bf); v = -c * c * v; }
    float r = LD(rc, 0, bf);
    float den = 1.0f + r * r * LD(rotor, b, bf);
    float res = v / den;
    if (bf) ((bf16*)out)[t] = __float2bfloat16(res);
    else    ((float*)out)[t] = res;
}

extern "C" void kernel_launch(void* const* d_in, const int* in_sizes, int n_in,
                              void* d_out, int out_size, void* d_ws, size_t ws_size,
                              hipStream_t stream) {
    const void* ligand_h = d_in[0];
    const void* target_h = d_in[1];
    const void* ligand_adj = d_in[2];
    const void* target_adj = d_in[3];
    const void* interaction_indice = d_in[4];
    const void* ligand_pos = d_in[5];
    const void* target_pos = d_in[6];
    const void* rotor = d_in[7];
    const void* ligand_vdw = d_in[8];
    const void* target_vdw = d_in[9];
    const void* ligand_valid = d_in[10];
    const void* target_valid = d_in[11];
    const void* emb_W = d_in[12];
    const void* gat_W = d_in[13];
    const void* gat_Wb = d_in[14];
    const void* gat_A = d_in[15];
    const void* gat_gW = d_in[16];
    const void* gat_gb = d_in[17];
    const void* vdwA_W1 = d_in[18];
    const void* vdwA_b1 = d_in[19];
    const void* vdwA_W2 = d_in[20];
    const void* vdwA_b2 = d_in[21];
    const void* dc_W1 = d_in[22];
    const void* dc_b1 = d_in[23];
    const void* dc_W2 = d_in[24];
    const void* dc_b2 = d_in[25];
    const void* hbond_coeff = d_in[26];
    const void* metal_coeff = d_in[27];
    const void* hydrophobic_coeff = d_in[28];
    const void* rotor_coeff = d_in[29];

    float* ws = (float*)d_ws;
    size_t off = 0;
    float* lig_x = ws + off;  off += (size_t)BB * LL * DIMD;   // x unified (lig, tgt)
    float* tgt_x = ws + off;  off += (size_t)BB * TT * DIMD;
    float* h_lig = ws + off;  off += (size_t)BB * LL * DIMD;   // h unified
    float* h_tgt = ws + off;  off += (size_t)BB * TT * DIMD;
    float* hA_lig = ws + off; off += (size_t)BB * LL * DIMD;   // hA unified (= P0)
    float* hA_tgt = ws + off; off += (size_t)BB * TT * DIMD;
    float* accum = ws + off;  off += 32;
    int* flagp = (int*)(ws + off); off += 2;
    float* e_buf = ws + off;  off += (size_t)BB * TT * TT;     // e1 target; later transposes
    float* e_lig = ws + off;  off += (size_t)BB * LL * LL;     // e1 ligand
    float* e2_buf = ws + off; off += (size_t)BB * TT * TT;     // e2 target
    float* e2_lig = ws + off; off += (size_t)BB * LL * LL;     // e2 ligand
    float* part1 = ws + off;  off += (size_t)BB * (LL + TT) * DIMD; // P1 unified
    float* part2 = ws + off;  off += (size_t)BB * (LL + TT) * DIMD; // P2 unified
    float* part3 = ws + off;  off += (size_t)BB * (LL + TT) * DIMD; // P3 unified
    float* projA = ws + off;  off += (size_t)BB * (LL + TT) * DIMD; // vdwA projection out
    float* cvw   = ws + off;  off += (size_t)CV_TOTAL;         // f32 weight copies
    float* part0 = hA_lig;       // P0 aliases hA (unified: hA_lig then hA_tgt contiguous)
    // pair-MLP projection outputs
    float* ligdc = h_lig;        // dc out reuses h region (rows: lig then tgt)
    float* tgtdc = h_tgt;
    float* ligA = projA;         // vdwA out in fresh buffer (P0 race avoidance)
    float* tgtA = projA + (size_t)BB * LL * DIMD;
    // transposed target projections reuse e_buf (dead after the GAT loop)
    float* tgtdcT = e_buf;
    float* tgtAT  = e_buf + (size_t)BB * DIMD * TT;
    float* wEmb = cvw + CV_EMBW;

    init_cvt<<<(CV_TOTAL + 255) / 256, 256, 0, stream>>>(
        (const unsigned int*)emb_W, emb_W, gat_W, gat_A, gat_Wb,
        gat_gW, gat_gb, dc_W1, vdwA_W1, cvw, accum, flagp);

    // embeddings: x = h @ emb_W (both sides, one launch; out rows contiguous)
    embed_both<<<BB * (LL + TT), DIMD, 0, stream>>>(ligand_h, target_h, wEmb, lig_x, 54, flagp);

    const long ROWSPLIT = (long)BB * LL;   // multiple of 4
    for (int i = 0; i < 3; ++i) {
        // [gate of layer i-1] + h = x@W+Wb ; hA = h@A   (both sides, one launch)
        gemm_hha_gate<<<BB * (LL + TT) / 4, 256, 0, stream>>>(
            lig_x, part0, part1, part2, part3, cvw, i, i > 0 ? 1 : 0, h_lig, hA_lig);
        // e = S1 + S2 (term split over blockIdx.y; symmetric mirror writes)
        esym_both<<<dim3(TGT_TILES + LIG_TILES, 2, BB), 256, 0, stream>>>(
            hA_tgt, h_tgt, e_buf, e2_buf, hA_lig, h_lig, e_lig, e2_lig);
        att_softmax_both<<<dim3(TT / 4 + LL / 4, BB), 256, 0, stream>>>(
            e_buf, e2_buf, e_lig, e2_lig, target_adj, ligand_adj, flagp);
        hp_gemm_both<<<dim3(20, 4, BB), 256, 0, stream>>>(
            e_buf, h_tgt, e_lig, h_lig, part0, part1, part2, part3);
    }

    // final gate (layer 2) + both pair-MLP projections in one launch
    proj_gate<<<dim3(BB * (LL + TT) / 4, 2), 256, 0, stream>>>(
        lig_x, part0, part1, part2, part3, cvw, dc_b1, vdwA_b1, ROWSPLIT,
        ligdc, ligA, flagp);

    // transpose target projections for coalesced pair_energy reads (one launch)
    transpose_both<<<dim3(TT / 32, DIMD / 32, 2 * BB), 256, 0, stream>>>(
        tgtdc, tgtdcT, tgtA, tgtAT);

    pair_energy<<<dim3(LL / 2, BB), 256, 0, stream>>>(
        ligdc, tgtdcT, ligA, tgtAT, dc_W2, dc_b2, vdwA_W2, vdwA_b2,
        ligand_pos, target_pos, ligand_vdw, target_vdw,
        ligand_valid, target_valid, interaction_indice, accum, flagp);

    finalize<<<1, 64, 0, stream>>>(accum, hbond_coeff, metal_coeff,
                                   hydrophobic_coeff, rotor_coeff, rotor, d_out, flagp);
}

// Round 12
// 342.961 us; speedup vs baseline: 1.2566x; 1.0885x over previous
//
#include <hip/hip_runtime.h>
#include <hip/hip_bf16.h>
#include <math.h>

typedef __hip_bfloat16 bf16;

#define DIMD 128
#define BB 8
#define LL 128
#define TT 512

// esym tile params
#define BMT 64
#define BKT 32
#define TGT_TILES 36   // 8*9/2 upper-tri tiles (N=512 / 64)
#define LIG_TILES 3    // 2*3/2 upper-tri tiles (N=128 / 64)

// cvt'd f32 weight region element offsets
#define CV_EMBW   0L
#define CV_GATW   (CV_EMBW + 54 * 128)
#define CV_GATA   (CV_GATW + 3 * 128 * 128)
#define CV_WB     (CV_GATA + 3 * 128 * 128)
#define CV_GGW    (CV_WB + 3 * 128)
#define CV_GGB    (CV_GGW + 3 * 2 * 128)
#define CV_DCW1   (CV_GGB + 4)
#define CV_VW1    (CV_DCW1 + 2 * 128 * 128)
#define CV_TOTAL  (CV_VW1 + 2 * 128 * 128)

// Runtime-dtype load of external inputs: bf==1 -> bf16, else f32.
__device__ __forceinline__ float LD(const void* p, long i, int bf) {
    if (bf) return __bfloat162float(((const bf16*)p)[i]);
    return ((const float*)p)[i];
}

// One-time: detect dtype (self-detect per block), zero accum, publish flagp,
// convert hot weights to f32 (branch-free GEMMs afterwards).
__global__ void init_cvt(const unsigned int* __restrict__ embw_raw,
                         const void* __restrict__ embW, const void* __restrict__ gatW,
                         const void* __restrict__ gatA, const void* __restrict__ gatWb,
                         const void* __restrict__ ggW, const void* __restrict__ ggb,
                         const void* __restrict__ dcW1, const void* __restrict__ vW1,
                         float* __restrict__ out, float* __restrict__ accum,
                         int* __restrict__ flagp) {
    __shared__ int cnts;
    int t = threadIdx.x;
    if (t == 0) cnts = 0;
    __syncthreads();
    unsigned int bword = (embw_raw[t] >> 8) & 0xffu;
    unsigned int e = bword & 0x7fu;
    if (e >= 0x38u && e <= 0x3fu) atomicAdd(&cnts, 1);
    __syncthreads();
    int bf = cnts > 128;
    if (blockIdx.x == 0) {
        if (t < 32) accum[t] = 0.0f;
        if (t == 0) *flagp = bf;
    }
    long i = (long)blockIdx.x * 256 + t;
    if (i >= CV_TOTAL) return;
    float v;
    if (i < CV_GATW)      v = LD(embW, i, bf);
    else if (i < CV_GATA) v = LD(gatW, i - CV_GATW, bf);
    else if (i < CV_WB)   v = LD(gatA, i - CV_GATA, bf);
    else if (i < CV_GGW)  v = LD(gatWb, i - CV_WB, bf);
    else if (i < CV_GGB)  v = LD(ggW, i - CV_GGW, bf);
    else if (i < CV_DCW1) { long j = i - CV_GGB; v = (j < 3) ? LD(ggb, j, bf) : 0.0f; }
    else if (i < CV_VW1)  v = LD(dcW1, i - CV_DCW1, bf);
    else                  v = LD(vW1, i - CV_VW1, bf);
    out[i] = v;
}

// Both-sides embedding: rows [0, BB*LL) from Xl, rest from Xt. K=54. f32 W.
__global__ void embed_both(const void* __restrict__ Xl, const void* __restrict__ Xt,
                           const float* __restrict__ Wf, float* __restrict__ out,
                           int K, const int* __restrict__ flagp) {
    __shared__ float xrow[DIMD];
    int bf = *flagp;
    int row = blockIdx.x;
    int d = threadIdx.x;
    const void* X; long r;
    if (row < BB * LL) { X = Xl; r = row; }
    else               { X = Xt; r = row - BB * LL; }
    if (d < K) xrow[d] = LD(X, r * K + d, bf);
    __syncthreads();
    float acc = 0.0f;
    for (int k = 0; k < K; ++k)
        acc = fmaf(xrow[k], Wf[(long)k * DIMD + d], acc);
    out[(long)row * DIMD + d] = acc;
}

// Fused [gate of previous layer] + h = x@W + Wb + hA = h@A.
// 4 rows/block, 256 threads. P0..P3 = split-K hp partials of the previous
// layer (unified row space, lig rows first). P0 aliases hA: each block reads
// its own rows before rewriting them.
__global__ void gemm_hha_gate(float* __restrict__ X, const float* __restrict__ P0,
                              const float* __restrict__ P1, const float* __restrict__ P2,
                              const float* __restrict__ P3, const float* __restrict__ cvw,
                              int layer, int dogate,
                              float* __restrict__ hout, float* __restrict__ hAout) {
    __shared__ float xs[4][DIMD];
    __shared__ float hs[4][DIMD];
    __shared__ float gred[4][2];
    long row0 = (long)blockIdx.x * 4;
    int d = threadIdx.x & 127, rg = threadIdx.x >> 7;
    int w = threadIdx.x >> 6, lane = threadIdx.x & 63;
    long r0 = row0 + rg * 2, r1 = r0 + 1;
    float xv0 = X[r0 * DIMD + d];
    float xv1 = X[r1 * DIMD + d];
    if (dogate) {
        const float* gW = cvw + CV_GGW + (long)(layer - 1) * 2 * DIMD;
        float gb = cvw[CV_GGB + (layer - 1)];
        float hp0 = fmaxf(P0[r0 * DIMD + d] + P1[r0 * DIMD + d]
                        + P2[r0 * DIMD + d] + P3[r0 * DIMD + d], 0.0f);
        float hp1 = fmaxf(P0[r1 * DIMD + d] + P1[r1 * DIMD + d]
                        + P2[r1 * DIMD + d] + P3[r1 * DIMD + d], 0.0f);
        float s0 = xv0 * gW[d] + hp0 * gW[DIMD + d];
        float s1 = xv1 * gW[d] + hp1 * gW[DIMD + d];
#pragma unroll
        for (int s = 32; s > 0; s >>= 1) { s0 += __shfl_xor(s0, s); s1 += __shfl_xor(s1, s); }
        if (lane == 0) { gred[rg * 2 + 0][w & 1] = s0; gred[rg * 2 + 1][w & 1] = s1; }
        __syncthreads();
        float g0 = gred[rg * 2 + 0][0] + gred[rg * 2 + 0][1] + gb;
        float g1 = gred[rg * 2 + 1][0] + gred[rg * 2 + 1][1] + gb;
        float c0 = 1.0f / (1.0f + expf(-g0));
        float c1 = 1.0f / (1.0f + expf(-g1));
        xv0 = c0 * xv0 + (1.0f - c0) * hp0;
        xv1 = c1 * xv1 + (1.0f - c1) * hp1;
        X[r0 * DIMD + d] = xv0;   // gated x for the next consumer
        X[r1 * DIMD + d] = xv1;
    }
    xs[rg * 2 + 0][d] = xv0;
    xs[rg * 2 + 1][d] = xv1;
    __syncthreads();
    const float* W = cvw + CV_GATW + (long)layer * DIMD * DIMD;
    const float* A = cvw + CV_GATA + (long)layer * DIMD * DIMD;
    float b = cvw[CV_WB + layer * DIMD + d];
    float h0 = b, h1 = b;
    const float* x0 = xs[rg * 2];
    const float* x1 = xs[rg * 2 + 1];
#pragma unroll 8
    for (int k = 0; k < DIMD; ++k) {
        float wv = W[(long)k * DIMD + d];
        h0 = fmaf(x0[k], wv, h0);
        h1 = fmaf(x1[k], wv, h1);
    }
    long ob = r0 * DIMD + d;
    hout[ob] = h0; hout[ob + DIMD] = h1;
    hs[rg * 2][d] = h0; hs[rg * 2 + 1][d] = h1;
    __syncthreads();
    float a0 = 0.0f, a1 = 0.0f;
    const float* g0p = hs[rg * 2];
    const float* g1p = hs[rg * 2 + 1];
#pragma unroll 8
    for (int k = 0; k < DIMD; ++k) {
        float wv = A[(long)k * DIMD + d];
        a0 = fmaf(g0p[k], wv, a0);
        a1 = fmaf(g1p[k], wv, a1);
    }
    hAout[ob] = a0;
    hAout[ob + DIMD] = a1;
}

// e = S1 + S2, S1 = hA·h^T, S2 = h·hA^T (each symmetric-pair-mirrorable).
// blockIdx.y selects the term (halves per-block work, doubles grid).
// Upper-triangle tiles + mirror writes. x: [0,36) target, [36,39) ligand.
__global__ void esym_both(const float* __restrict__ hA_t, const float* __restrict__ h_t,
                          float* __restrict__ e1_t, float* __restrict__ e2_t,
                          const float* __restrict__ hA_l, const float* __restrict__ h_l,
                          float* __restrict__ e1_l, float* __restrict__ e2_l) {
    __shared__ float At[BKT][BMT + 4];
    __shared__ float Bt[BKT][BMT + 4];
    int idx = blockIdx.x, half = blockIdx.y, b = blockIdx.z, t = threadIdx.x;
    const float *hA, *h; float* e; int N;
    if (idx < TGT_TILES) { hA = hA_t; h = h_t; e = half ? e2_t : e1_t; N = TT; }
    else { idx -= TGT_TILES; hA = hA_l; h = h_l; e = half ? e2_l : e1_l; N = LL; }
    int jt = (int)((sqrtf(8.0f * idx + 1.0f) - 1.0f) * 0.5f);
    while ((jt + 1) * (jt + 2) / 2 <= idx) ++jt;
    while (jt * (jt + 1) / 2 > idx) --jt;
    int kt = idx - jt * (jt + 1) / 2;   // kt <= jt
    const float* hAb = hA + (long)b * N * DIMD;
    const float* hb  = h  + (long)b * N * DIMD;
    const float* Ap = half ? hb : hAb;
    const float* Bp = half ? hAb : hb;
    int tm = t & 15, tn = t >> 4;
    int k4 = (t & 7) * 4;
    int row0 = t >> 3;
    float acc[4][4];
#pragma unroll
    for (int i = 0; i < 4; ++i)
#pragma unroll
        for (int jj = 0; jj < 4; ++jj) acc[i][jj] = 0.0f;

#pragma unroll
    for (int c = 0; c < 4; ++c) {
        int ko = c * BKT;
        __syncthreads();
#pragma unroll
        for (int rr = 0; rr < 2; ++rr) {
            int row = row0 + rr * 32;
            float4 av = *(const float4*)&Ap[(long)(jt * BMT + row) * DIMD + ko + k4];
            float4 bv = *(const float4*)&Bp[(long)(kt * BMT + row) * DIMD + ko + k4];
            At[k4 + 0][row] = av.x; At[k4 + 1][row] = av.y;
            At[k4 + 2][row] = av.z; At[k4 + 3][row] = av.w;
            Bt[k4 + 0][row] = bv.x; Bt[k4 + 1][row] = bv.y;
            Bt[k4 + 2][row] = bv.z; Bt[k4 + 3][row] = bv.w;
        }
        __syncthreads();
#pragma unroll
        for (int k = 0; k < BKT; ++k) {
            float4 a4 = *(const float4*)&At[k][tm * 4];
            float4 b4 = *(const float4*)&Bt[k][tn * 4];
            float A[4] = {a4.x, a4.y, a4.z, a4.w};
            float Bv[4] = {b4.x, b4.y, b4.z, b4.w};
#pragma unroll
            for (int i = 0; i < 4; ++i)
#pragma unroll
                for (int jj = 0; jj < 4; ++jj)
                    acc[i][jj] = fmaf(A[i], Bv[jj], acc[i][jj]);
        }
    }
    long ebN = (long)b * N;
    long ebase = (ebN + jt * BMT + tm * 4) * N + kt * BMT + tn * 4;
#pragma unroll
    for (int i = 0; i < 4; ++i) {
        float4 v;
        v.x = acc[i][0]; v.y = acc[i][1]; v.z = acc[i][2]; v.w = acc[i][3];
        *(float4*)&e[ebase + (long)i * N] = v;
    }
    if (jt != kt) {   // mirror (transpose) — sum of halves stays symmetric
        long mbase = (ebN + kt * BMT + tn * 4) * N + jt * BMT + tm * 4;
#pragma unroll
        for (int jj = 0; jj < 4; ++jj) {
            float4 v;
            v.x = acc[0][jj]; v.y = acc[1][jj]; v.z = acc[2][jj]; v.w = acc[3][jj];
            *(float4*)&e[mbase + (long)jj * N] = v;
        }
    }
}

// att row softmax, one WAVE per row. Reads e1+e2, writes normalized att to e1.
template<int CNT>
__device__ __forceinline__ void softmax_row(float* __restrict__ e1row,
                                            const float* __restrict__ e2row,
                                            const void* __restrict__ adj,
                                            long adjbase, int bf) {
    int lane = threadIdx.x & 63;
    float vals[CNT], av[CNT];
    float m = -3.4e38f;
#pragma unroll
    for (int i = 0; i < CNT; ++i) {
        int k = lane + i * 64;
        float a = LD(adj, adjbase + k, bf);
        float v = (a > 0.0f) ? (e1row[k] + e2row[k]) : -9e15f;
        av[i] = a; vals[i] = v;
        m = fmaxf(m, v);
    }
#pragma unroll
    for (int s = 32; s > 0; s >>= 1) m = fmaxf(m, __shfl_xor(m, s));
    float sum = 0.0f;
#pragma unroll
    for (int i = 0; i < CNT; ++i) { vals[i] = expf(vals[i] - m); sum += vals[i]; }
#pragma unroll
    for (int s = 32; s > 0; s >>= 1) sum += __shfl_xor(sum, s);
    float inv = 1.0f / sum;
#pragma unroll
    for (int i = 0; i < CNT; ++i)
        e1row[lane + i * 64] = vals[i] * av[i] * inv;
}

// x < TT/4: target rows; else ligand rows. 4 waves = 4 rows per block.
__global__ void att_softmax_both(float* __restrict__ e1_t, const float* __restrict__ e2_t,
                                 float* __restrict__ e1_l, const float* __restrict__ e2_l,
                                 const void* __restrict__ adj_t, const void* __restrict__ adj_l,
                                 const int* __restrict__ flagp) {
    int bf = *flagp;
    int b = blockIdx.y, x = blockIdx.x;
    int jr = threadIdx.x >> 6;
    if (x < TT / 4) {
        int j = x * 4 + jr;
        long base = ((long)b * TT + j) * TT;
        softmax_row<8>(e1_t + base, e2_t + base, adj_t, base, bf);
    } else {
        int j = (x - TT / 4) * 4 + jr;
        long base = ((long)b * LL + j) * LL;
        softmax_row<2>(e1_l + base, e2_l + base, adj_l, base, bf);
    }
}

// Partial hp GEMM: P[kc][row][d] = sum over k-quarter of att[j][k]*h[k][d]
// BM=32, BN=128, BK=32, 256 threads, 4x4 acc, split-K=4 via blockIdx.y.
// Grid x: [0,16) target row-tiles, [16,20) ligand row-tiles.
// P0..P3 are UNIFIED row-space bases (lig rows first, then tgt).
__global__ void hp_gemm_both(const float* __restrict__ att_t, const float* __restrict__ h_t,
                             const float* __restrict__ att_l, const float* __restrict__ h_l,
                             float* __restrict__ P0, float* __restrict__ P1,
                             float* __restrict__ P2, float* __restrict__ P3) {
    __shared__ float At[32][36];
    __shared__ float Ht[32][DIMD];
    int jt = blockIdx.x, kc = blockIdx.y, b = blockIdx.z;
    int t = threadIdx.x;
    const float *att, *h; int N; long rowbase;
    if (jt < 16) { att = att_t; h = h_t; N = TT; rowbase = (long)BB * LL + (long)b * TT; }
    else { jt -= 16; att = att_l; h = h_l; N = LL; rowbase = (long)b * LL; }
    const float* attb = att + (long)b * N * N;
    const float* hb = h + (long)b * N * DIMD;
    int tm = t & 7, tn = t >> 3;
    float acc[4][4] = {};
    int kchunk = N / 4;
    int kbeg = kc * kchunk;
    int ar = t >> 3;
    int ac4 = (t & 7) * 4;
    int hk = t >> 5;
    int hc4 = (t & 31) * 4;
    for (int k0 = kbeg; k0 < kbeg + kchunk; k0 += 32) {
        __syncthreads();
        float4 av = *(const float4*)&attb[(long)(jt * 32 + ar) * N + k0 + ac4];
        At[ac4 + 0][ar] = av.x; At[ac4 + 1][ar] = av.y;
        At[ac4 + 2][ar] = av.z; At[ac4 + 3][ar] = av.w;
#pragma unroll
        for (int p = 0; p < 4; ++p)
            *(float4*)&Ht[hk + p * 8][hc4] = *(const float4*)&hb[(long)(k0 + hk + p * 8) * DIMD + hc4];
        __syncthreads();
#pragma unroll
        for (int k = 0; k < 32; ++k) {
            float4 a4 = *(const float4*)&At[k][tm * 4];
            float4 h4 = *(const float4*)&Ht[k][tn * 4];
            float A[4] = {a4.x, a4.y, a4.z, a4.w};
            float H[4] = {h4.x, h4.y, h4.z, h4.w};
#pragma unroll
            for (int i = 0; i < 4; ++i)
#pragma unroll
                for (int jj = 0; jj < 4; ++jj)
                    acc[i][jj] = fmaf(A[i], H[jj], acc[i][jj]);
        }
    }
    float* outp = (kc == 0) ? P0 : (kc == 1) ? P1 : (kc == 2) ? P2 : P3;
    long obase = (rowbase + jt * 32 + tm * 4) * DIMD + tn * 4;
#pragma unroll
    for (int i = 0; i < 4; ++i) {
        float4 v; v.x = acc[i][0]; v.y = acc[i][1]; v.z = acc[i][2]; v.w = acc[i][3];
        *(float4*)&outp[obase + (long)i * DIMD] = v;
    }
}

// Final-layer gate + both pair-MLP projections. blockIdx.y: 0=dc, 1=vdwA.
__global__ void proj_gate(const float* __restrict__ X, const float* __restrict__ P0,
                          const float* __restrict__ P1, const float* __restrict__ P2,
                          const float* __restrict__ P3, const float* __restrict__ cvw,
                          const void* __restrict__ bdc, const void* __restrict__ bA,
                          long rowsplit, float* __restrict__ outdc, float* __restrict__ outA,
                          const int* __restrict__ flagp) {
    __shared__ float xs[4][DIMD];
    __shared__ float gred[4][2];
    int bf = *flagp;
    long row0 = (long)blockIdx.x * 4;
    int d = threadIdx.x & 127, rg = threadIdx.x >> 7;
    int w = threadIdx.x >> 6, lane = threadIdx.x & 63;
    long r0 = row0 + rg * 2, r1 = r0 + 1;
    float xv0 = X[r0 * DIMD + d];
    float xv1 = X[r1 * DIMD + d];
    {
        const float* gW = cvw + CV_GGW + 2L * 2 * DIMD;
        float gb = cvw[CV_GGB + 2];
        float hp0 = fmaxf(P0[r0 * DIMD + d] + P1[r0 * DIMD + d]
                        + P2[r0 * DIMD + d] + P3[r0 * DIMD + d], 0.0f);
        float hp1 = fmaxf(P0[r1 * DIMD + d] + P1[r1 * DIMD + d]
                        + P2[r1 * DIMD + d] + P3[r1 * DIMD + d], 0.0f);
        float s0 = xv0 * gW[d] + hp0 * gW[DIMD + d];
        float s1 = xv1 * gW[d] + hp1 * gW[DIMD + d];
#pragma unroll
        for (int s = 32; s > 0; s >>= 1) { s0 += __shfl_xor(s0, s); s1 += __shfl_xor(s1, s); }
        if (lane == 0) { gred[rg * 2 + 0][w & 1] = s0; gred[rg * 2 + 1][w & 1] = s1; }
        __syncthreads();
        float g0 = gred[rg * 2 + 0][0] + gred[rg * 2 + 0][1] + gb;
        float g1 = gred[rg * 2 + 1][0] + gred[rg * 2 + 1][1] + gb;
        float c0 = 1.0f / (1.0f + expf(-g0));
        float c1 = 1.0f / (1.0f + expf(-g1));
        xv0 = c0 * xv0 + (1.0f - c0) * hp0;
        xv1 = c1 * xv1 + (1.0f - c1) * hp1;
    }
    xs[rg * 2 + 0][d] = xv0;
    xs[rg * 2 + 1][d] = xv1;
    __syncthreads();
    const float* Wf = (blockIdx.y == 0) ? (cvw + CV_DCW1) : (cvw + CV_VW1);
    const void* bias = (blockIdx.y == 0) ? bdc : bA;
    float* out = (blockIdx.y == 0) ? outdc : outA;
    int sideb = row0 >= rowsplit;
    const float* W = Wf + (sideb ? (long)DIMD * DIMD : 0);
    float b0 = sideb ? 0.0f : LD(bias, d, bf);
    float a0 = b0, a1 = b0;
    const float* x0 = xs[rg * 2];
    const float* x1 = xs[rg * 2 + 1];
#pragma unroll 8
    for (int k = 0; k < DIMD; ++k) {
        float wv = W[(long)k * DIMD + d];
        a0 = fmaf(x0[k], wv, a0);
        a1 = fmaf(x1[k], wv, a1);
    }
    long ob = r0 * DIMD + d;
    out[ob] = a0;
    out[ob + DIMD] = a1;
}

// Both transposes in one launch: z<BB -> (in0->out0, b=z), else (in1->out1).
__global__ void transpose_both(const float* __restrict__ in0, float* __restrict__ out0,
                               const float* __restrict__ in1, float* __restrict__ out1) {
    __shared__ float tile[32][33];
    int z = blockIdx.z;
    const float* in; float* outT; int b;
    if (z < BB) { in = in0; outT = out0; b = z; }
    else        { in = in1; outT = out1; b = z - BB; }
    int n0 = blockIdx.x * 32;
    int d0 = blockIdx.y * 32;
    int t = threadIdx.x;
    int tx = t & 31, ty = t >> 5;
    for (int r = ty; r < 32; r += 8)
        tile[r][tx] = in[((long)b * TT + n0 + r) * DIMD + d0 + tx];
    __syncthreads();
    for (int r = ty; r < 32; r += 8)
        outT[((long)b * DIMD + d0 + r) * TT + n0 + tx] = tile[tx][r];
}

// Pair energies. Block = (b, 2 ligand rows); lane handles tt = 2t, 2t+1.
// All end-phase scalars (tpos/trad/tval/ii) PREFETCHED before the dot loop so
// their HBM latency hides under the 128-iter L2-bound MLP dot phase.
__global__ void pair_energy(const float* __restrict__ ligdc, const float* __restrict__ tgtdcT,
                            const float* __restrict__ ligA, const float* __restrict__ tgtAT,
                            const void* __restrict__ dcW2, const void* __restrict__ dcb2,
                            const void* __restrict__ AW2, const void* __restrict__ Ab2,
                            const void* __restrict__ lpos, const void* __restrict__ tpos,
                            const void* __restrict__ lrad, const void* __restrict__ trad,
                            const void* __restrict__ lval, const void* __restrict__ tval,
                            const void* __restrict__ ii, float* __restrict__ accum,
                            const int* __restrict__ flagp) {
    int bf = *flagp;
    int l0 = blockIdx.x * 2, b = blockIdx.y, t = threadIdx.x;
    __shared__ __align__(16) float sdc0[DIMD], sdc1[DIMD], sA0[DIMD], sA1[DIMD];
    __shared__ __align__(16) float w2dc[DIMD], w2A[DIMD];
    __shared__ float redw[4][4];
    if (t < DIMD) {
        sdc0[t] = ligdc[((long)b * LL + l0) * DIMD + t];
        sA0[t]  = ligA [((long)b * LL + l0) * DIMD + t];
        w2dc[t] = LD(dcW2, t, bf);
        w2A[t]  = LD(AW2, t, bf);
    } else {
        int u = t - DIMD;
        sdc1[u] = ligdc[((long)b * LL + l0 + 1) * DIMD + u];
        sA1[u]  = ligA [((long)b * LL + l0 + 1) * DIMD + u];
    }
    int tt0 = t * 2;
    // ---- prefetch (issued before the dot loop; consumed after it) ----
    float tx0 = LD(tpos, ((long)b * TT + tt0) * 3 + 0, bf);
    float ty0 = LD(tpos, ((long)b * TT + tt0) * 3 + 1, bf);
    float tz0 = LD(tpos, ((long)b * TT + tt0) * 3 + 2, bf);
    float tx1 = LD(tpos, ((long)b * TT + tt0 + 1) * 3 + 0, bf);
    float ty1 = LD(tpos, ((long)b * TT + tt0 + 1) * 3 + 1, bf);
    float tz1 = LD(tpos, ((long)b * TT + tt0 + 1) * 3 + 2, bf);
    float tr0 = LD(trad, (long)b * TT + tt0, bf);
    float tr1 = LD(trad, (long)b * TT + tt0 + 1, bf);
    float tv0 = LD(tval, (long)b * TT + tt0, bf);
    float tv1 = LD(tval, (long)b * TT + tt0 + 1, bf);
    long iiA0 = ((long)(b * 3 + 0) * LL + l0) * TT;
    long iiB0 = ((long)(b * 3 + 1) * LL + l0) * TT;
    long iiC0 = ((long)(b * 3 + 2) * LL + l0) * TT;
    long iiA1 = iiA0 + TT, iiB1 = iiB0 + TT, iiC1 = iiC0 + TT;
    float iA00 = LD(ii, iiA0 + tt0, bf), iA01 = LD(ii, iiA0 + tt0 + 1, bf);
    float iA10 = LD(ii, iiA1 + tt0, bf), iA11 = LD(ii, iiA1 + tt0 + 1, bf);
    float iB00 = LD(ii, iiB0 + tt0, bf), iB01 = LD(ii, iiB0 + tt0 + 1, bf);
    float iB10 = LD(ii, iiB1 + tt0, bf), iB11 = LD(ii, iiB1 + tt0 + 1, bf);
    float iC00 = LD(ii, iiC0 + tt0, bf), iC01 = LD(ii, iiC0 + tt0 + 1, bf);
    float iC10 = LD(ii, iiC1 + tt0, bf), iC11 = LD(ii, iiC1 + tt0 + 1, bf);
    float lx0 = LD(lpos, ((long)b * LL + l0) * 3 + 0, bf);
    float ly0 = LD(lpos, ((long)b * LL + l0) * 3 + 1, bf);
    float lz0 = LD(lpos, ((long)b * LL + l0) * 3 + 2, bf);
    float lx1 = LD(lpos, ((long)b * LL + l0 + 1) * 3 + 0, bf);
    float ly1 = LD(lpos, ((long)b * LL + l0 + 1) * 3 + 1, bf);
    float lz1 = LD(lpos, ((long)b * LL + l0 + 1) * 3 + 2, bf);
    float lr0 = LD(lrad, (long)b * LL + l0, bf);
    float lr1 = LD(lrad, (long)b * LL + l0 + 1, bf);
    float lv0 = LD(lval, (long)b * LL + l0, bf);
    float lv1 = LD(lval, (long)b * LL + l0 + 1, bf);
    float cdcb2 = LD(dcb2, 0, bf), cab2 = LD(Ab2, 0, bf);
    __syncthreads();
    // ---- MLP dot loop (L2-bound; hides the prefetch latency) ----
    const float* tdT = tgtdcT + (long)b * DIMD * TT;
    const float* taT = tgtAT  + (long)b * DIMD * TT;
    float adc00 = 0.0f, adc01 = 0.0f, adc10 = 0.0f, adc11 = 0.0f;
    float aA00 = 0.0f, aA01 = 0.0f, aA10 = 0.0f, aA11 = 0.0f;
    for (int i4 = 0; i4 < DIMD; i4 += 4) {
        float4 wd = *(const float4*)&w2dc[i4];
        float4 wa = *(const float4*)&w2A[i4];
        float4 v0d = *(const float4*)&sdc0[i4];
        float4 v1d = *(const float4*)&sdc1[i4];
        float4 v0a = *(const float4*)&sA0[i4];
        float4 v1a = *(const float4*)&sA1[i4];
        float wdv[4] = {wd.x, wd.y, wd.z, wd.w};
        float wav[4] = {wa.x, wa.y, wa.z, wa.w};
        float s0d[4] = {v0d.x, v0d.y, v0d.z, v0d.w};
        float s1d[4] = {v1d.x, v1d.y, v1d.z, v1d.w};
        float s0a[4] = {v0a.x, v0a.y, v0a.z, v0a.w};
        float s1a[4] = {v1a.x, v1a.y, v1a.z, v1a.w};
#pragma unroll
        for (int j = 0; j < 4; ++j) {
            float2 td = *(const float2*)&tdT[(long)(i4 + j) * TT + tt0];
            float2 ta = *(const float2*)&taT[(long)(i4 + j) * TT + tt0];
            adc00 = fmaf(fmaxf(td.x + s0d[j], 0.0f), wdv[j], adc00);
            adc01 = fmaf(fmaxf(td.y + s0d[j], 0.0f), wdv[j], adc01);
            adc10 = fmaf(fmaxf(td.x + s1d[j], 0.0f), wdv[j], adc10);
            adc11 = fmaf(fmaxf(td.y + s1d[j], 0.0f), wdv[j], adc11);
            aA00 = fmaf(fmaxf(ta.x + s0a[j], 0.0f), wav[j], aA00);
            aA01 = fmaf(fmaxf(ta.y + s0a[j], 0.0f), wav[j], aA01);
            aA10 = fmaf(fmaxf(ta.x + s1a[j], 0.0f), wav[j], aA10);
            aA11 = fmaf(fmaxf(ta.y + s1a[j], 0.0f), wav[j], aA11);
        }
    }
    // ---- energies (all inputs already in registers) ----
    float p0 = 0.0f, p1 = 0.0f, p2 = 0.0f, p3 = 0.0f;
#pragma unroll
    for (int jj = 0; jj < 2; ++jj) {
        float tx = jj ? tx1 : tx0, ty = jj ? ty1 : ty0, tz = jj ? tz1 : tz0;
        float tr = jj ? tr1 : tr0, tv = jj ? tv1 : tv0;
#pragma unroll
        for (int li = 0; li < 2; ++li) {
            float dx = (li ? lx1 : lx0) - tx;
            float dy = (li ? ly1 : ly0) - ty;
            float dz = (li ? lz1 : lz0) - tz;
            float dm = sqrtf(dx * dx + dy * dy + dz * dz + 1e-10f);
            if (dm < 0.5f) dm = 1e10f;
            float adcv = jj ? (li ? adc11 : adc01) : (li ? adc10 : adc00);
            float aAv  = jj ? (li ? aA11  : aA01)  : (li ? aA10  : aA00);
            float dev = tanhf(adcv + cdcb2) * 0.2f;
            float vdws = (li ? lr1 : lr0) + tr + dev;
            float dm0 = (vdws < 1e-4f) ? 1.0f : vdws;
            float ratio = dm0 / dm;
            float r2 = ratio * ratio, r6 = r2 * r2 * r2, r12 = r6 * r6;
            float en = fminf(r12 - 2.0f * r6, 100.0f) * (li ? lv1 : lv0) * tv;
            float As = 1.0f / (1.0f + expf(-(aAv + cab2)));
            As = As * (0.0356f - 0.0178f) + 0.0178f;
            p0 = fmaf(As, en, p0);
            float dd = dm - vdws;
            float ramp = fminf(fmaxf(dd * (1.0f / -0.7f), 0.0f), 1.0f);
            float ramp2 = fminf(fmaxf(-dd + 1.5f, 0.0f), 1.0f);
            float vA = jj ? (li ? iA11 : iA01) : (li ? iA10 : iA00);
            float vB = jj ? (li ? iB11 : iB01) : (li ? iB10 : iB00);
            float vC = jj ? (li ? iC11 : iC01) : (li ? iC10 : iC00);
            p1 = fmaf(ramp, vA, p1);
            p2 = fmaf(ramp, vB, p2);
            p3 = fmaf(ramp2, vC, p3);
        }
    }
    // ---- reduction: wave shfl -> 4x4 LDS -> atomics (2 barriers total) ----
#pragma unroll
    for (int s = 32; s > 0; s >>= 1) {
        p0 += __shfl_xor(p0, s);
        p1 += __shfl_xor(p1, s);
        p2 += __shfl_xor(p2, s);
        p3 += __shfl_xor(p3, s);
    }
    int w = t >> 6, lane = t & 63;
    if (lane == 0) { redw[w][0] = p0; redw[w][1] = p1; redw[w][2] = p2; redw[w][3] = p3; }
    __syncthreads();
    if (t < 4) {
        float v = redw[0][t] + redw[1][t] + redw[2][t] + redw[3][t];
        atomicAdd(&accum[b * 4 + t], v);
    }
}

__global__ void finalize(const float* __restrict__ accum, const void* __restrict__ hb,
                         const void* __restrict__ mc, const void* __restrict__ hyd,
                         const void* __restrict__ rc, const void* __restrict__ rotor,
                         void* __restrict__ out, const int* __restrict__ flagp) {
    int bf = *flagp;
    int t = threadIdx.x;  // 64 threads, use first 32
    if (t >= 32) return;
    int b = t >> 2, e = t & 3;
    float v = accum[t];
    if (e == 1) { float c = LD(hb, 0, bf);  v = -c * c * v; }
    else if (e == 2) { float c = LD(mc, 0, bf);  v = -c * c * v; }
    else if (e == 3) { float c = LD(hyd, 0, bf); v = -c * c * v; }
    float r = LD(rc, 0, bf);
    float den = 1.0f + r * r * LD(rotor, b, bf);
    float res = v / den;
    if (bf) ((bf16*)out)[t] = __float2bfloat16(res);
    else    ((float*)out)[t] = res;
}

extern "C" void kernel_launch(void* const* d_in, const int* in_sizes, int n_in,
                              void* d_out, int out_size, void* d_ws, size_t ws_size,
                              hipStream_t stream) {
    const void* ligand_h = d_in[0];
    const void* target_h = d_in[1];
    const void* ligand_adj = d_in[2];
    const void* target_adj = d_in[3];
    const void* interaction_indice = d_in[4];
    const void* ligand_pos = d_in[5];
    const void* target_pos = d_in[6];
    const void* rotor = d_in[7];
    const void* ligand_vdw = d_in[8];
    const void* target_vdw = d_in[9];
    const void* ligand_valid = d_in[10];
    const void* target_valid = d_in[11];
    const void* emb_W = d_in[12];
    const void* gat_W = d_in[13];
    const void* gat_Wb = d_in[14];
    const void* gat_A = d_in[15];
    const void* gat_gW = d_in[16];
    const void* gat_gb = d_in[17];
    const void* vdwA_W1 = d_in[18];
    const void* vdwA_b1 = d_in[19];
    const void* vdwA_W2 = d_in[20];
    const void* vdwA_b2 = d_in[21];
    const void* dc_W1 = d_in[22];
    const void* dc_b1 = d_in[23];
    const void* dc_W2 = d_in[24];
    const void* dc_b2 = d_in[25];
    const void* hbond_coeff = d_in[26];
    const void* metal_coeff = d_in[27];
    const void* hydrophobic_coeff = d_in[28];
    const void* rotor_coeff = d_in[29];

    float* ws = (float*)d_ws;
    size_t off = 0;
    float* lig_x = ws + off;  off += (size_t)BB * LL * DIMD;   // x unified (lig, tgt)
    float* tgt_x = ws + off;  off += (size_t)BB * TT * DIMD;
    float* h_lig = ws + off;  off += (size_t)BB * LL * DIMD;   // h unified
    float* h_tgt = ws + off;  off += (size_t)BB * TT * DIMD;
    float* hA_lig = ws + off; off += (size_t)BB * LL * DIMD;   // hA unified (= P0)
    float* hA_tgt = ws + off; off += (size_t)BB * TT * DIMD;
    float* accum = ws + off;  off += 32;
    int* flagp = (int*)(ws + off); off += 2;
    float* e_buf = ws + off;  off += (size_t)BB * TT * TT;     // e1 target; later transposes
    float* e_lig = ws + off;  off += (size_t)BB * LL * LL;     // e1 ligand
    float* e2_buf = ws + off; off += (size_t)BB * TT * TT;     // e2 target
    float* e2_lig = ws + off; off += (size_t)BB * LL * LL;     // e2 ligand
    float* part1 = ws + off;  off += (size_t)BB * (LL + TT) * DIMD; // P1 unified
    float* part2 = ws + off;  off += (size_t)BB * (LL + TT) * DIMD; // P2 unified
    float* part3 = ws + off;  off += (size_t)BB * (LL + TT) * DIMD; // P3 unified
    float* projA = ws + off;  off += (size_t)BB * (LL + TT) * DIMD; // vdwA projection out
    float* cvw   = ws + off;  off += (size_t)CV_TOTAL;         // f32 weight copies
    float* part0 = hA_lig;       // P0 aliases hA (unified: hA_lig then hA_tgt contiguous)
    // pair-MLP projection outputs
    float* ligdc = h_lig;        // dc out reuses h region (rows: lig then tgt)
    float* tgtdc = h_tgt;
    float* ligA = projA;         // vdwA out in fresh buffer (P0 race avoidance)
    float* tgtA = projA + (size_t)BB * LL * DIMD;
    // transposed target projections reuse e_buf (dead after the GAT loop)
    float* tgtdcT = e_buf;
    float* tgtAT  = e_buf + (size_t)BB * DIMD * TT;
    float* wEmb = cvw + CV_EMBW;

    init_cvt<<<(CV_TOTAL + 255) / 256, 256, 0, stream>>>(
        (const unsigned int*)emb_W, emb_W, gat_W, gat_A, gat_Wb,
        gat_gW, gat_gb, dc_W1, vdwA_W1, cvw, accum, flagp);

    // embeddings: x = h @ emb_W (both sides, one launch; out rows contiguous)
    embed_both<<<BB * (LL + TT), DIMD, 0, stream>>>(ligand_h, target_h, wEmb, lig_x, 54, flagp);

    const long ROWSPLIT = (long)BB * LL;   // multiple of 4
    for (int i = 0; i < 3; ++i) {
        // [gate of layer i-1] + h = x@W+Wb ; hA = h@A   (both sides, one launch)
        gemm_hha_gate<<<BB * (LL + TT) / 4, 256, 0, stream>>>(
            lig_x, part0, part1, part2, part3, cvw, i, i > 0 ? 1 : 0, h_lig, hA_lig);
        // e = S1 + S2 (term split over blockIdx.y; symmetric mirror writes)
        esym_both<<<dim3(TGT_TILES + LIG_TILES, 2, BB), 256, 0, stream>>>(
            hA_tgt, h_tgt, e_buf, e2_buf, hA_lig, h_lig, e_lig, e2_lig);
        att_softmax_both<<<dim3(TT / 4 + LL / 4, BB), 256, 0, stream>>>(
            e_buf, e2_buf, e_lig, e2_lig, target_adj, ligand_adj, flagp);
        hp_gemm_both<<<dim3(20, 4, BB), 256, 0, stream>>>(
            e_buf, h_tgt, e_lig, h_lig, part0, part1, part2, part3);
    }

    // final gate (layer 2) + both pair-MLP projections in one launch
    proj_gate<<<dim3(BB * (LL + TT) / 4, 2), 256, 0, stream>>>(
        lig_x, part0, part1, part2, part3, cvw, dc_b1, vdwA_b1, ROWSPLIT,
        ligdc, ligA, flagp);

    // transpose target projections for coalesced pair_energy reads (one launch)
    transpose_both<<<dim3(TT / 32, DIMD / 32, 2 * BB), 256, 0, stream>>>(
        tgtdc, tgtdcT, tgtA, tgtAT);

    pair_energy<<<dim3(LL / 2, BB), 256, 0, stream>>>(
        ligdc, tgtdcT, ligA, tgtAT, dc_W2, dc_b2, vdwA_W2, vdwA_b2,
        ligand_pos, target_pos, ligand_vdw, target_vdw,
        ligand_valid, target_valid, interaction_indice, accum, flagp);

    finalize<<<1, 64, 0, stream>>>(accum, hbond_coeff, metal_coeff,
                                   hydrophobic_coeff, rotor_coeff, rotor, d_out, flagp);
}